// Round 12
// baseline (269.875 us; speedup 1.0000x reference)
//
#include <hip/hip_runtime.h>
#include <hip/hip_fp16.h>
#include <math.h>

#define BATCH 8
#define HW_N 409600          // 640*640
#define HW4 (HW_N / 4)       // 102400
#define NBLK 200             // blocks per batch; grid = 1600, 7 blocks/CU co-resident
#define TOTB (NBLK * BATCH)

// k1s per-batch slots
#define NP 56
#define J_AK   0             // kernel dice: sum pk*gk*km
#define J_BK   1
#define J_CK   2
#define J_AT   3             // text dice sums
#define J_BTP  4
#define J_BTN  5
#define J_CPOS 6
#define J_CNEG 7
#define J_CNTK 8             // +(s-1)
#define J_CNTT 16            // +(s-1)
#define J_SUMK 24            // +(s-1)*4+c

typedef float f4v __attribute__((ext_vector_type(4)));
typedef int   i4v __attribute__((ext_vector_type(4)));

__device__ __forceinline__ unsigned f2key(float x) {
    unsigned u = __float_as_uint(x);
    return (u & 0x80000000u) ? ~u : (u | 0x80000000u);
}
__device__ __forceinline__ float key2f(unsigned k) {
    unsigned u = (k & 0x80000000u) ? (k & 0x7fffffffu) : ~k;
    return __uint_as_float(u);
}
__device__ __forceinline__ float wred64(float v) {
#pragma unroll
    for (int o = 32; o > 0; o >>= 1) v += __shfl_xor(v, o, 64);
    return v;
}
__device__ __forceinline__ float wredmin64(float v) {
#pragma unroll
    for (int o = 32; o > 0; o >>= 1) v = fminf(v, __shfl_xor(v, o, 64));
    return v;
}

// ---------------------------------------------------------------------------
// K1_FUSED: persistent kernel. Phase 1 = R6's proven 42µs body; Fv retained
// in LDS as f16 (cannot spill), labels in 2 scalar regs. Km sums -> global
// device atomics. Grid-wide spin barrier (all 1600 blocks co-resident).
// Phase 2 = aggregation loss from LDS. No pk8 plane, no second Fv pass.
// ---------------------------------------------------------------------------
__global__ __launch_bounds__(256, 7)
void k1_fused(const f4v* __restrict__ Tl, const f4v* __restrict__ Kl,
              const f4v* __restrict__ Fv, const f4v* __restrict__ Tm,
              const i4v* __restrict__ Ltk, const i4v* __restrict__ Lkk,
              float* __restrict__ ksum,        // [B][40]: cnt_k[8], sum_k[32]
              float* __restrict__ part,        // [B][16][NBLK]
              unsigned* __restrict__ minkeyinv,
              unsigned* __restrict__ bar,
              float* __restrict__ slg) {       // [B][8]
    const int tid = threadIdx.x;
    const int wid = tid >> 6, lane = tid & 63;
    const int b  = (int)(blockIdx.x & 7u);     // XCD-affine batches
    const int bx = (int)(blockIdx.x >> 3);
    const long base4 = (long)b * HW4;
    const long f04 = (long)b * 4 * HW4;

    __shared__ __half2 fvh[2][4][2][256];      // retained Fv, 16 KB
    __shared__ float sK[32];
    __shared__ unsigned cKs[8], cTs[8];
    __shared__ float wacc[4][8];
    __shared__ float wmin[4];
    __shared__ float kraw[40];
    __shared__ float Kml[32];

    if (tid < 32) sK[tid] = 0.f;
    else if (tid < 40) cKs[tid - 32] = 0u;
    else if (tid < 48) cTs[tid - 40] = 0u;
    __syncthreads();

    const int i0 = bx * 512 + tid;
    const int i1 = i0 + 256;

    // ---- issue ALL 20 loads, then pin (R6 structure) ----
    const f4v tlA = Tl[base4 + i0],  tlB = Tl[base4 + i1];
    const f4v klA = Kl[base4 + i0],  klB = Kl[base4 + i1];
    const f4v tmA = Tm[base4 + i0],  tmB = Tm[base4 + i1];
    const i4v ltA = Ltk[base4 + i0], ltB = Ltk[base4 + i1];
    const i4v lkA = Lkk[base4 + i0], lkB = Lkk[base4 + i1];
    const f4v f0A = Fv[f04 + i0],            f0B = Fv[f04 + i1];
    const f4v f1A = Fv[f04 + HW4 + i0],      f1B = Fv[f04 + HW4 + i1];
    const f4v f2A = Fv[f04 + 2 * HW4 + i0],  f2B = Fv[f04 + 2 * HW4 + i1];
    const f4v f3A = Fv[f04 + 3 * HW4 + i0],  f3B = Fv[f04 + 3 * HW4 + i1];
    asm volatile("" ::
        "v"(tlA.x), "v"(tlB.x), "v"(klA.x), "v"(klB.x), "v"(tmA.x), "v"(tmB.x),
        "v"(f0A.x), "v"(f0B.x), "v"(f1A.x), "v"(f1B.x),
        "v"(f2A.x), "v"(f2B.x), "v"(f3A.x), "v"(f3B.x),
        "v"(ltA.x), "v"(ltB.x), "v"(lkA.x), "v"(lkB.x));

    float r0 = 0.f, r1 = 0.f, r2 = 0.f, r3 = 0.f, r4 = 0.f, r5 = 0.f;
    float cpos = 0.f, cneg = 0.f;
    float vmin = INFINITY;
    unsigned ltp0 = 0u, ltp1 = 0u;             // 4-bit lt per pixel

#pragma unroll
    for (int it = 0; it < 2; ++it) {
        const f4v tl4 = it ? tlB : tlA;
        const f4v kl4 = it ? klB : klA;
        const f4v tm4 = it ? tmB : tmA;
        const i4v lt4 = it ? ltB : ltA;
        const i4v lk4 = it ? lkB : lkA;
        const f4v F0v = it ? f0B : f0A;
        const f4v F1v = it ? f1B : f1A;
        const f4v F2v = it ? f2B : f2A;
        const f4v F3v = it ? f3B : f3A;
        unsigned lp = 0u;
#pragma unroll
        for (int p = 0; p < 4; ++p) {
            float tl = tl4[p], kl = kl4[p], m = tm4[p];
            int ltk = lt4[p], lkk = lk4[p];
            bool tmb = m > 0.5f;
            bool selt = tl > 0.f;      // sigmoid(x)>0.5 <=> x>0
            bool selk = kl > 0.f;
            bool pos = ltk > 0;        // gt_text == (gt_text_key > 0)
            float gkf = (lkk > 0) ? 1.f : 0.f;
            float km = (selt && tmb) ? 1.f : 0.f;
            float pkv = 1.f / (1.f + __expf(-kl));
            float ptv = 1.f / (1.f + __expf(-tl));
            r0 = fmaf(pkv * gkf, km, r0);
            r1 = fmaf(pkv * pkv, km, r1);
            r2 = fmaf(gkf, km, r2);
            float ptm = (pos && tmb) ? 1.f : 0.f;
            float ntm = (!pos && tmb) ? 1.f : 0.f;
            r3 = fmaf(ptv, ptm, r3);
            r4 = fmaf(ptv * ptv, ptm, r4);
            r5 = fmaf(ptv * ptv, ntm, r5);
            cpos += ptm;
            cneg += pos ? 0.f : 1.f;
            vmin = fminf(vmin, pos ? INFINITY : tl);
            int lk = (selk && tmb) ? lkk : 0;
            if (lk > 0) {
                atomicAdd(&sK[(lk - 1) * 4 + 0], F0v[p]);
                atomicAdd(&sK[(lk - 1) * 4 + 1], F1v[p]);
                atomicAdd(&sK[(lk - 1) * 4 + 2], F2v[p]);
                atomicAdd(&sK[(lk - 1) * 4 + 3], F3v[p]);
                atomicAdd(&cKs[lk - 1], 1u);
            }
            unsigned lt = (selt && tmb) ? (unsigned)ltk : 0u;
            if (lt) atomicAdd(&cTs[lt - 1], 1u);
            lp |= lt << (4 * p);
        }
        if (it == 0) ltp0 = lp; else ltp1 = lp;
        fvh[it][0][0][tid] = __floats2half2_rn(F0v[0], F0v[1]);
        fvh[it][0][1][tid] = __floats2half2_rn(F0v[2], F0v[3]);
        fvh[it][1][0][tid] = __floats2half2_rn(F1v[0], F1v[1]);
        fvh[it][1][1][tid] = __floats2half2_rn(F1v[2], F1v[3]);
        fvh[it][2][0][tid] = __floats2half2_rn(F2v[0], F2v[1]);
        fvh[it][2][1][tid] = __floats2half2_rn(F2v[2], F2v[3]);
        fvh[it][3][0][tid] = __floats2half2_rn(F3v[0], F3v[1]);
        fvh[it][3][1][tid] = __floats2half2_rn(F3v[2], F3v[3]);
    }

    r0 = wred64(r0); r1 = wred64(r1); r2 = wred64(r2);
    r3 = wred64(r3); r4 = wred64(r4); r5 = wred64(r5);
    cpos = wred64(cpos); cneg = wred64(cneg);
    vmin = wredmin64(vmin);
    if (lane == 0) {
        wacc[wid][0] = r0; wacc[wid][1] = r1; wacc[wid][2] = r2;
        wacc[wid][3] = r3; wacc[wid][4] = r4; wacc[wid][5] = r5;
        wacc[wid][6] = cpos; wacc[wid][7] = cneg;
        wmin[wid] = vmin;
    }
    __syncthreads();
    if (tid < 8) {
        float v = wacc[0][tid] + wacc[1][tid] + wacc[2][tid] + wacc[3][tid];
        part[((size_t)b * 16 + tid) * NBLK + bx] = v;
    } else if (tid < 16) {
        part[((size_t)b * 16 + tid) * NBLK + bx] = (float)cTs[tid - 8];
    }
    if (tid >= 64 && tid < 104) {
        int t = tid - 64;
        atomicAdd(&ksum[b * 40 + t], t < 8 ? (float)cKs[t] : sK[t - 8]);
    }
    if (tid == 104) {
        float mn = fminf(fminf(wmin[0], wmin[1]), fminf(wmin[2], wmin[3]));
        if (mn < INFINITY) atomicMax(&minkeyinv[b], ~f2key(mn));
    }
    __syncthreads();   // barrier implies vmcnt(0): ksum atomics performed

    // ---- grid-wide barrier: all blocks co-resident by construction ----
    if (tid == 0) {
        __hip_atomic_fetch_add(bar, 1u, __ATOMIC_RELAXED,
                               __HIP_MEMORY_SCOPE_AGENT);
        while (__hip_atomic_load(bar, __ATOMIC_RELAXED,
                                 __HIP_MEMORY_SCOPE_AGENT) < (unsigned)TOTB)
            __builtin_amdgcn_s_sleep(2);
    }
    __syncthreads();

    // ---- phase 2: kernel means, then aggregation loss from LDS ----
    if (tid < 40)
        kraw[tid] = __hip_atomic_load(&ksum[b * 40 + tid], __ATOMIC_RELAXED,
                                      __HIP_MEMORY_SCOPE_AGENT);
    __syncthreads();
    if (tid < 32) Kml[tid] = kraw[8 + tid] / fmaxf(kraw[tid >> 2], 1.f);
    __syncthreads();

    float sl8[8] = {0.f, 0.f, 0.f, 0.f, 0.f, 0.f, 0.f, 0.f};
#pragma unroll
    for (int it = 0; it < 2; ++it) {
        const unsigned lp = it ? ltp1 : ltp0;
#pragma unroll
        for (int p = 0; p < 4; ++p) {
            int lt = (int)((lp >> (4 * p)) & 0xFu);
            float2 c0 = __half22float2(fvh[it][0][p >> 1][tid]);
            float2 c1 = __half22float2(fvh[it][1][p >> 1][tid]);
            float2 c2 = __half22float2(fvh[it][2][p >> 1][tid]);
            float2 c3 = __half22float2(fvh[it][3][p >> 1][tid]);
            float F0 = (p & 1) ? c0.y : c0.x;
            float F1 = (p & 1) ? c1.y : c1.x;
            float F2 = (p & 1) ? c2.y : c2.x;
            float F3 = (p & 1) ? c3.y : c3.x;
            int kb = (lt > 0 ? lt - 1 : 0) * 4;
            float d0 = F0 - Kml[kb + 0];
            float d1 = F1 - Kml[kb + 1];
            float d2 = F2 - Kml[kb + 2];
            float d3 = F3 - Kml[kb + 3];
            float d = sqrtf(fmaf(d0, d0, fmaf(d1, d1, fmaf(d2, d2, d3 * d3))));
            float t = fmaxf(d - 0.5f, 0.f);
            float pl = __logf(fmaf(t, t, 1.f));
#pragma unroll
            for (int s = 1; s <= 8; ++s)
                sl8[s - 1] = fmaf((lt == s) ? 1.f : 0.f, pl, sl8[s - 1]);
        }
    }
#pragma unroll
    for (int j = 0; j < 8; ++j) sl8[j] = wred64(sl8[j]);
    if (lane == 0) {
#pragma unroll
        for (int j = 0; j < 8; ++j) wacc[wid][j] = sl8[j];
    }
    __syncthreads();
    if (tid < 8) {
        float v = wacc[0][tid] + wacc[1][tid] + wacc[2][tid] + wacc[3][tid];
        if (v != 0.f) atomicAdd(&slg[b * 8 + tid], v);
    }
}

// ---------------------------------------------------------------------------
// K1R: reduce part[] + copy ksum -> k1s; OHEM decision; kernel means.
// ---------------------------------------------------------------------------
__global__ __launch_bounds__(256)
void k1_reduce(const float* __restrict__ part, const float* __restrict__ ksum,
               const unsigned* __restrict__ minkeyinv,
               float* __restrict__ k1s, float* __restrict__ kms,
               float* __restrict__ thr, unsigned* __restrict__ kval,
               unsigned* __restrict__ fb) {
    const int b = blockIdx.x;
    const int tid = threadIdx.x, wid = tid >> 6, lane = tid & 63;
    __shared__ float ss[16];
    for (int j = wid; j < 16; j += 4) {
        const float* p = part + ((size_t)b * 16 + j) * NBLK;
        float v = 0.f;
        for (int i = lane; i < NBLK; i += 64) v += p[i];
        v = wred64(v);
        if (lane == 0) ss[j] = v;
    }
    __syncthreads();
    if (tid == 0) {
        unsigned pos = (unsigned)(ss[6] + 0.5f);
        unsigned neg = (unsigned)(ss[7] + 0.5f);
        unsigned k = min(3u * pos, neg);
        kval[b] = k;
        if (pos == 0u || k == 0u) { thr[b] = -INFINITY; fb[b] = 1u; }
        else if (k == neg)        { thr[b] = key2f(~minkeyinv[b]); fb[b] = 1u; }
        else                      { fb[b] = 0u; }   // rare: radix path
    }
    if (tid < 16)
        k1s[b * NP + (tid < 8 ? tid : J_CNTT + (tid - 8))] = ss[tid];
    if (tid >= 64 && tid < 104) {
        int t = tid - 64;
        k1s[b * NP + (t < 8 ? J_CNTK + t : J_SUMK + (t - 8))] = ksum[b * 40 + t];
    }
    if (tid >= 128 && tid < 160) {
        int t = tid - 128;
        kms[b * 32 + t] = ksum[b * 40 + 8 + t] /
                          fmaxf(ksum[b * 40 + (t >> 2)], 1.f);
    }
}

// ---------------------------------------------------------------------------
// K_RARE: exact k-th-largest negative logit via 4-pass radix select (raw
// inputs). Early-exits in the common (fb=1) case.
// ---------------------------------------------------------------------------
__global__ __launch_bounds__(256)
void k_rare(const float* __restrict__ Tl, const int* __restrict__ Ltk,
            const unsigned* __restrict__ fb, const unsigned* __restrict__ kval,
            float* __restrict__ thr) {
    const int b = blockIdx.x;
    if (fb[b]) return;
    __shared__ unsigned hist[256];
    __shared__ unsigned sj, spre;
    const long base = (long)b * HW_N;
    if (threadIdx.x == 0) { sj = kval[b]; spre = 0u; }
    __syncthreads();
    for (int pass = 0; pass < 4; ++pass) {
        const int shift = 24 - 8 * pass;
        hist[threadIdx.x] = 0u;
        __syncthreads();
        const unsigned pref = spre;
        for (int i = threadIdx.x; i < HW_N; i += 256) {
            if (Ltk[base + i] > 0) continue;   // pos pixel
            unsigned key = f2key(Tl[base + i]);
            if (pass == 0 || (key >> (shift + 8)) == pref)
                atomicAdd(&hist[(key >> shift) & 0xFFu], 1u);
        }
        __syncthreads();
        if (threadIdx.x == 0) {
            unsigned j = sj, cum = 0;
            for (int d = 255; d >= 0; --d) {
                cum += hist[d];
                if (cum >= j) {
                    sj = j - (cum - hist[d]);
                    spre = (pref << 8) | (unsigned)d;
                    break;
                }
            }
        }
        __syncthreads();
    }
    if (threadIdx.x == 0) thr[b] = key2f(spre);
}

// ---------------------------------------------------------------------------
// K_NEGFIX: rare path only — SUBTRACT pt^2 of excluded negatives (tl < thr).
// ---------------------------------------------------------------------------
__global__ __launch_bounds__(256)
void k_negfix(const f4v* __restrict__ Tl, const f4v* __restrict__ Tm,
              const i4v* __restrict__ Ltk, const unsigned* __restrict__ fb,
              const float* __restrict__ thr, float* __restrict__ k1s) {
    const int b = blockIdx.y;
    if (fb[b]) return;
    const int tid = threadIdx.x;
    const long base4 = (long)b * HW4;
    const float tb = thr[b];
    float acc = 0.f;
#pragma unroll
    for (int j = 0; j < 4; ++j) {
        const int i4 = blockIdx.x * 1024 + j * 256 + tid;
        const f4v tl4 = Tl[base4 + i4];
        const f4v tm4 = Tm[base4 + i4];
        const i4v lt4 = Ltk[base4 + i4];
#pragma unroll
        for (int p = 0; p < 4; ++p) {
            bool tmb = tm4[p] > 0.5f;
            bool neg = lt4[p] <= 0;
            float tl = tl4[p];
            if (neg && tmb && tl < tb) {
                float pt = 1.f / (1.f + __expf(-tl));
                acc = fmaf(pt, pt, acc);
            }
        }
    }
    acc = wred64(acc);
    __shared__ float wa[4];
    if ((tid & 63) == 0) wa[tid >> 6] = acc;
    __syncthreads();
    if (tid == 0) {
        float s = wa[0] + wa[1] + wa[2] + wa[3];
        if (s != 0.f) atomicAdd(&k1s[b * NP + J_BTN], -s);
    }
}

// ---------------------------------------------------------------------------
// K6: final combine -> scalar loss.
// ---------------------------------------------------------------------------
__global__ __launch_bounds__(512)
void k6_final(const float* __restrict__ k1s, const float* __restrict__ kms,
              const float* __restrict__ slg, float* __restrict__ out) {
    const int tid = threadIdx.x;
    const int b = tid >> 6, lane = tid & 63;
    __shared__ float KmS[BATCH * 32];
    __shared__ float laS[BATCH], ldS[BATCH];
    if (tid < BATCH * 32) KmS[tid] = kms[tid];
    __syncthreads();
    const float* s1 = k1s + b * NP;

    float aggs = 0.f, aggc = 0.f;
    if (lane >= 1 && lane <= 8) {
        float ctv = s1[J_CNTT + lane - 1];
        float ckv = s1[J_CNTK + lane - 1];
        if (ctv > 0.f && ckv > 0.f) {
            aggs = slg[b * 8 + lane - 1] / fmaxf(ctv, 1.f);
            aggc = 1.f;
        }
    }
    float diss = 0.f, disc = 0.f;
    {
        int i = 1 + (lane >> 3), j = 1 + (lane & 7);
        if (i != j && s1[J_CNTK + i - 1] > 0.f && s1[J_CNTK + j - 1] > 0.f) {
            float d2 = 0.f;
#pragma unroll
            for (int c = 0; c < 4; ++c) {
                float df = KmS[b * 32 + (i - 1) * 4 + c] -
                           KmS[b * 32 + (j - 1) * 4 + c];
                d2 = fmaf(df, df, d2);
            }
            float kd = sqrtf(d2);
            float t = fmaxf(3.f - kd, 0.f);
            diss = logf(t * t + 1.f);
            disc = 1.f;
        }
    }
    aggs = wred64(aggs); aggc = wred64(aggc);
    diss = wred64(diss); disc = wred64(disc);
    if (lane == 0) {
        laS[b] = aggs / fmaxf(aggc, 1.f);
        ldS[b] = diss / fmaxf(disc, 1.f);
    }
    __syncthreads();
    if (tid == 0) {
        float Lt = 0.f, Lk = 0.f, La = 0.f, Ld = 0.f;
        for (int bb = 0; bb < BATCH; ++bb) {
            const float* a = k1s + bb * NP;
            Lk += 1.f - 2.f * a[J_AK] / ((a[J_BK] + 1e-6f) + (a[J_CK] + 1e-6f));
            float btv = a[J_BTP] + a[J_BTN];
            Lt += 1.f - 2.f * a[J_AT] / ((btv + 1e-6f) + (a[J_CPOS] + 1e-6f));
            La += laS[bb]; Ld += ldS[bb];
        }
        out[0] = Lt / BATCH + 0.5f * (Lk / BATCH) + 0.25f * (La / BATCH + Ld / BATCH);
    }
}

// ---------------------------------------------------------------------------
extern "C" void kernel_launch(void* const* d_in, const int* in_sizes, int n_in,
                              void* d_out, int out_size, void* d_ws, size_t ws_size,
                              hipStream_t stream) {
    (void)in_sizes; (void)n_in; (void)out_size; (void)ws_size;
    const f4v* Tl = (const f4v*)d_in[0];   // pre_text_logits
    const f4v* Kl = (const f4v*)d_in[1];   // pre_kernel_logits
    const f4v* Fv = (const f4v*)d_in[2];   // similarity_vector [B,C,H,W]
    const f4v* Tm = (const f4v*)d_in[5];   // train_mask
    const i4v* Ltk = (const i4v*)d_in[6];  // gt_text_key
    const i4v* Lkk = (const i4v*)d_in[7];  // gt_kernel_key
    float* out = (float*)d_out;

    // ws layout (4B units). memset region first: slg, minkeyinv, bar, ksum.
    float* slg = (float*)d_ws;                           // 64
    unsigned* minkeyinv = (unsigned*)(slg + 64);         // 8
    unsigned* bar = minkeyinv + BATCH;                   // 8 (1 used)
    float* ksum = (float*)(bar + BATCH);                 // 8*40 = 320
    float* thr = ksum + BATCH * 40;                      // 8
    unsigned* kval = (unsigned*)(thr + BATCH);           // 8
    unsigned* fb = kval + BATCH;                         // 8
    float* k1s = (float*)(fb + BATCH);                   // 8*56 = 448
    float* kms = k1s + BATCH * NP;                       // 8*32 = 256
    float* part = kms + BATCH * 32;                      // 8*16*200 = 25600

    hipMemsetAsync(d_ws, 0, (size_t)(64 + 8 + 8 + 320) * 4, stream);

    k1_fused<<<TOTB, 256, 0, stream>>>(Tl, Kl, Fv, Tm, Ltk, Lkk,
                                       ksum, part, minkeyinv, bar, slg);
    k1_reduce<<<BATCH, 256, 0, stream>>>(part, ksum, minkeyinv,
                                         k1s, kms, thr, kval, fb);
    k_rare<<<BATCH, 256, 0, stream>>>((const float*)d_in[0],
                                      (const int*)d_in[6], fb, kval, thr);
    k_negfix<<<dim3(100, BATCH), 256, 0, stream>>>(Tl, Tm, Ltk, fb, thr, k1s);
    k6_final<<<1, 512, 0, stream>>>(k1s, kms, slg, out);
}

// Round 13
// 110.573 us; speedup vs baseline: 2.4407x; 2.4407x over previous
//
#include <hip/hip_runtime.h>
#include <hip/hip_fp16.h>
#include <math.h>

#define BATCH 8
#define HW_N 409600          // 640*640
#define HW4 (HW_N / 4)       // 102400
#define NBLK 100             // blocks per batch; grid = 800 <= 1024 co-resident @4/CU
#define TOTB (NBLK * BATCH)

// k1s per-batch slots
#define NP 56
#define J_AK   0             // kernel dice: sum pk*gk*km
#define J_BK   1
#define J_CK   2
#define J_AT   3             // text dice sums
#define J_BTP  4
#define J_BTN  5
#define J_CPOS 6
#define J_CNEG 7
#define J_CNTK 8             // +(s-1)
#define J_CNTT 16            // +(s-1)
#define J_SUMK 24            // +(s-1)*4+c

typedef float f4v __attribute__((ext_vector_type(4)));
typedef int   i4v __attribute__((ext_vector_type(4)));

__device__ __forceinline__ unsigned f2key(float x) {
    unsigned u = __float_as_uint(x);
    return (u & 0x80000000u) ? ~u : (u | 0x80000000u);
}
__device__ __forceinline__ float key2f(unsigned k) {
    unsigned u = (k & 0x80000000u) ? (k & 0x7fffffffu) : ~k;
    return __uint_as_float(u);
}
__device__ __forceinline__ float wred64(float v) {
#pragma unroll
    for (int o = 32; o > 0; o >>= 1) v += __shfl_xor(v, o, 64);
    return v;
}
__device__ __forceinline__ float wredmin64(float v) {
#pragma unroll
    for (int o = 32; o > 0; o >>= 1) v = fminf(v, __shfl_xor(v, o, 64));
    return v;
}

// ---------------------------------------------------------------------------
// K1_FUSED: persistent kernel, 4 blocks/CU co-resident (VGPR cap 128 -> no
// spill). Phase 1: per-iteration loads, Fv retained in LDS as f16, labels in
// 4 unrolled regs. Km sums -> device atomics. Agent-scope spin barrier.
// Phase 2: aggregation loss from LDS. No pk8 plane, no second Fv pass.
// ---------------------------------------------------------------------------
__global__ __launch_bounds__(256, 4)
void k1_fused(const f4v* __restrict__ Tl, const f4v* __restrict__ Kl,
              const f4v* __restrict__ Fv, const f4v* __restrict__ Tm,
              const i4v* __restrict__ Ltk, const i4v* __restrict__ Lkk,
              float* __restrict__ ksum,        // [B][40]: cnt_k[8], sum_k[32]
              float* __restrict__ part,        // [B][16][NBLK]
              unsigned* __restrict__ minkeyinv,
              unsigned* __restrict__ bar,
              float* __restrict__ slg) {       // [B][8]
    const int tid = threadIdx.x;
    const int wid = tid >> 6, lane = tid & 63;
    const int b  = (int)(blockIdx.x & 7u);     // XCD-affine batches
    const int bx = (int)(blockIdx.x >> 3);
    const long base4 = (long)b * HW4;
    const long f04 = (long)b * 4 * HW4;

    __shared__ __half2 fvh[4][4][2][256];      // retained Fv, 32 KB
    __shared__ float sK[32];
    __shared__ unsigned cKs[8], cTs[8];
    __shared__ float wacc[4][8];
    __shared__ float wmin[4];
    __shared__ float kraw[40];
    __shared__ float Kml[32];

    if (tid < 32) sK[tid] = 0.f;
    else if (tid < 40) cKs[tid - 32] = 0u;
    else if (tid < 48) cTs[tid - 40] = 0u;
    __syncthreads();

    float r0 = 0.f, r1 = 0.f, r2 = 0.f, r3 = 0.f, r4 = 0.f, r5 = 0.f;
    float cpos = 0.f, cneg = 0.f;
    float vmin = INFINITY;
    unsigned lp0 = 0u, lp1 = 0u, lp2 = 0u, lp3 = 0u;   // 4-bit lt per pixel

#pragma unroll
    for (int it = 0; it < 4; ++it) {
        const int i4 = bx * 1024 + it * 256 + tid;
        const f4v tl4 = Tl[base4 + i4];
        const f4v kl4 = Kl[base4 + i4];
        const f4v tm4 = Tm[base4 + i4];
        const i4v lt4 = Ltk[base4 + i4];
        const i4v lk4 = Lkk[base4 + i4];
        const f4v F0v = Fv[f04 + i4];
        const f4v F1v = Fv[f04 + HW4 + i4];
        const f4v F2v = Fv[f04 + 2 * HW4 + i4];
        const f4v F3v = Fv[f04 + 3 * HW4 + i4];
        unsigned lp = 0u;
#pragma unroll
        for (int p = 0; p < 4; ++p) {
            float tl = tl4[p], kl = kl4[p], m = tm4[p];
            int ltk = lt4[p], lkk = lk4[p];
            bool tmb = m > 0.5f;
            bool selt = tl > 0.f;      // sigmoid(x)>0.5 <=> x>0
            bool selk = kl > 0.f;
            bool pos = ltk > 0;        // gt_text == (gt_text_key > 0)
            float gkf = (lkk > 0) ? 1.f : 0.f;
            float km = (selt && tmb) ? 1.f : 0.f;
            float pkv = 1.f / (1.f + __expf(-kl));
            float ptv = 1.f / (1.f + __expf(-tl));
            r0 = fmaf(pkv * gkf, km, r0);
            r1 = fmaf(pkv * pkv, km, r1);
            r2 = fmaf(gkf, km, r2);
            float ptm = (pos && tmb) ? 1.f : 0.f;
            float ntm = (!pos && tmb) ? 1.f : 0.f;
            r3 = fmaf(ptv, ptm, r3);
            r4 = fmaf(ptv * ptv, ptm, r4);
            r5 = fmaf(ptv * ptv, ntm, r5);
            cpos += ptm;
            cneg += pos ? 0.f : 1.f;
            vmin = fminf(vmin, pos ? INFINITY : tl);
            int lk = (selk && tmb) ? lkk : 0;
            if (lk > 0) {
                atomicAdd(&sK[(lk - 1) * 4 + 0], F0v[p]);
                atomicAdd(&sK[(lk - 1) * 4 + 1], F1v[p]);
                atomicAdd(&sK[(lk - 1) * 4 + 2], F2v[p]);
                atomicAdd(&sK[(lk - 1) * 4 + 3], F3v[p]);
                atomicAdd(&cKs[lk - 1], 1u);
            }
            unsigned lt = (selt && tmb) ? (unsigned)ltk : 0u;
            if (lt) atomicAdd(&cTs[lt - 1], 1u);
            lp |= lt << (4 * p);
        }
        if (it == 0) lp0 = lp; else if (it == 1) lp1 = lp;
        else if (it == 2) lp2 = lp; else lp3 = lp;
        fvh[it][0][0][tid] = __floats2half2_rn(F0v[0], F0v[1]);
        fvh[it][0][1][tid] = __floats2half2_rn(F0v[2], F0v[3]);
        fvh[it][1][0][tid] = __floats2half2_rn(F1v[0], F1v[1]);
        fvh[it][1][1][tid] = __floats2half2_rn(F1v[2], F1v[3]);
        fvh[it][2][0][tid] = __floats2half2_rn(F2v[0], F2v[1]);
        fvh[it][2][1][tid] = __floats2half2_rn(F2v[2], F2v[3]);
        fvh[it][3][0][tid] = __floats2half2_rn(F3v[0], F3v[1]);
        fvh[it][3][1][tid] = __floats2half2_rn(F3v[2], F3v[3]);
    }

    r0 = wred64(r0); r1 = wred64(r1); r2 = wred64(r2);
    r3 = wred64(r3); r4 = wred64(r4); r5 = wred64(r5);
    cpos = wred64(cpos); cneg = wred64(cneg);
    vmin = wredmin64(vmin);
    if (lane == 0) {
        wacc[wid][0] = r0; wacc[wid][1] = r1; wacc[wid][2] = r2;
        wacc[wid][3] = r3; wacc[wid][4] = r4; wacc[wid][5] = r5;
        wacc[wid][6] = cpos; wacc[wid][7] = cneg;
        wmin[wid] = vmin;
    }
    __syncthreads();
    if (tid < 8) {
        float v = wacc[0][tid] + wacc[1][tid] + wacc[2][tid] + wacc[3][tid];
        part[((size_t)b * 16 + tid) * NBLK + bx] = v;
    } else if (tid < 16) {
        part[((size_t)b * 16 + tid) * NBLK + bx] = (float)cTs[tid - 8];
    }
    if (tid >= 64 && tid < 104) {
        int t = tid - 64;
        atomicAdd(&ksum[b * 40 + t], t < 8 ? (float)cKs[t] : sK[t - 8]);
    }
    if (tid == 104) {
        float mn = fminf(fminf(wmin[0], wmin[1]), fminf(wmin[2], wmin[3]));
        if (mn < INFINITY) atomicMax(&minkeyinv[b], ~f2key(mn));
    }
    __syncthreads();   // implies vmcnt(0): ksum atomics performed

    // ---- grid-wide barrier: all 800 blocks co-resident by construction ----
    if (tid == 0) {
        __hip_atomic_fetch_add(bar, 1u, __ATOMIC_RELAXED,
                               __HIP_MEMORY_SCOPE_AGENT);
        while (__hip_atomic_load(bar, __ATOMIC_RELAXED,
                                 __HIP_MEMORY_SCOPE_AGENT) < (unsigned)TOTB)
            __builtin_amdgcn_s_sleep(2);
    }
    __syncthreads();

    // ---- phase 2: kernel means, then aggregation loss from LDS ----
    if (tid < 40)
        kraw[tid] = __hip_atomic_load(&ksum[b * 40 + tid], __ATOMIC_RELAXED,
                                      __HIP_MEMORY_SCOPE_AGENT);
    __syncthreads();
    if (tid < 32) Kml[tid] = kraw[8 + tid] / fmaxf(kraw[tid >> 2], 1.f);
    __syncthreads();

    float sl8[8] = {0.f, 0.f, 0.f, 0.f, 0.f, 0.f, 0.f, 0.f};
#pragma unroll
    for (int it = 0; it < 4; ++it) {
        const unsigned lp = (it == 0) ? lp0 : (it == 1) ? lp1
                            : (it == 2) ? lp2 : lp3;
#pragma unroll
        for (int p = 0; p < 4; ++p) {
            int lt = (int)((lp >> (4 * p)) & 0xFu);
            float2 c0 = __half22float2(fvh[it][0][p >> 1][tid]);
            float2 c1 = __half22float2(fvh[it][1][p >> 1][tid]);
            float2 c2 = __half22float2(fvh[it][2][p >> 1][tid]);
            float2 c3 = __half22float2(fvh[it][3][p >> 1][tid]);
            float F0 = (p & 1) ? c0.y : c0.x;
            float F1 = (p & 1) ? c1.y : c1.x;
            float F2 = (p & 1) ? c2.y : c2.x;
            float F3 = (p & 1) ? c3.y : c3.x;
            int kb = (lt > 0 ? lt - 1 : 0) * 4;
            float d0 = F0 - Kml[kb + 0];
            float d1 = F1 - Kml[kb + 1];
            float d2 = F2 - Kml[kb + 2];
            float d3 = F3 - Kml[kb + 3];
            float d = sqrtf(fmaf(d0, d0, fmaf(d1, d1, fmaf(d2, d2, d3 * d3))));
            float t = fmaxf(d - 0.5f, 0.f);
            float pl = __logf(fmaf(t, t, 1.f));
#pragma unroll
            for (int s = 1; s <= 8; ++s)
                sl8[s - 1] = fmaf((lt == s) ? 1.f : 0.f, pl, sl8[s - 1]);
        }
    }
#pragma unroll
    for (int j = 0; j < 8; ++j) sl8[j] = wred64(sl8[j]);
    if (lane == 0) {
#pragma unroll
        for (int j = 0; j < 8; ++j) wacc[wid][j] = sl8[j];
    }
    __syncthreads();
    if (tid < 8) {
        float v = wacc[0][tid] + wacc[1][tid] + wacc[2][tid] + wacc[3][tid];
        if (v != 0.f) atomicAdd(&slg[b * 8 + tid], v);
    }
}

// ---------------------------------------------------------------------------
// K1R: reduce part[] + copy ksum -> k1s; OHEM decision; kernel means.
// ---------------------------------------------------------------------------
__global__ __launch_bounds__(256)
void k1_reduce(const float* __restrict__ part, const float* __restrict__ ksum,
               const unsigned* __restrict__ minkeyinv,
               float* __restrict__ k1s, float* __restrict__ kms,
               float* __restrict__ thr, unsigned* __restrict__ kval,
               unsigned* __restrict__ fb) {
    const int b = blockIdx.x;
    const int tid = threadIdx.x, wid = tid >> 6, lane = tid & 63;
    __shared__ float ss[16];
    for (int j = wid; j < 16; j += 4) {
        const float* p = part + ((size_t)b * 16 + j) * NBLK;
        float v = 0.f;
        for (int i = lane; i < NBLK; i += 64) v += p[i];
        v = wred64(v);
        if (lane == 0) ss[j] = v;
    }
    __syncthreads();
    if (tid == 0) {
        unsigned pos = (unsigned)(ss[6] + 0.5f);
        unsigned neg = (unsigned)(ss[7] + 0.5f);
        unsigned k = min(3u * pos, neg);
        kval[b] = k;
        if (pos == 0u || k == 0u) { thr[b] = -INFINITY; fb[b] = 1u; }
        else if (k == neg)        { thr[b] = key2f(~minkeyinv[b]); fb[b] = 1u; }
        else                      { fb[b] = 0u; }   // rare: radix path
    }
    if (tid < 16)
        k1s[b * NP + (tid < 8 ? tid : J_CNTT + (tid - 8))] = ss[tid];
    if (tid >= 64 && tid < 104) {
        int t = tid - 64;
        k1s[b * NP + (t < 8 ? J_CNTK + t : J_SUMK + (t - 8))] = ksum[b * 40 + t];
    }
    if (tid >= 128 && tid < 160) {
        int t = tid - 128;
        kms[b * 32 + t] = ksum[b * 40 + 8 + t] /
                          fmaxf(ksum[b * 40 + (t >> 2)], 1.f);
    }
}

// ---------------------------------------------------------------------------
// K_RARE: exact k-th-largest negative logit via 4-pass radix select (raw
// inputs). Early-exits in the common (fb=1) case.
// ---------------------------------------------------------------------------
__global__ __launch_bounds__(256)
void k_rare(const float* __restrict__ Tl, const int* __restrict__ Ltk,
            const unsigned* __restrict__ fb, const unsigned* __restrict__ kval,
            float* __restrict__ thr) {
    const int b = blockIdx.x;
    if (fb[b]) return;
    __shared__ unsigned hist[256];
    __shared__ unsigned sj, spre;
    const long base = (long)b * HW_N;
    if (threadIdx.x == 0) { sj = kval[b]; spre = 0u; }
    __syncthreads();
    for (int pass = 0; pass < 4; ++pass) {
        const int shift = 24 - 8 * pass;
        hist[threadIdx.x] = 0u;
        __syncthreads();
        const unsigned pref = spre;
        for (int i = threadIdx.x; i < HW_N; i += 256) {
            if (Ltk[base + i] > 0) continue;   // pos pixel
            unsigned key = f2key(Tl[base + i]);
            if (pass == 0 || (key >> (shift + 8)) == pref)
                atomicAdd(&hist[(key >> shift) & 0xFFu], 1u);
        }
        __syncthreads();
        if (threadIdx.x == 0) {
            unsigned j = sj, cum = 0;
            for (int d = 255; d >= 0; --d) {
                cum += hist[d];
                if (cum >= j) {
                    sj = j - (cum - hist[d]);
                    spre = (pref << 8) | (unsigned)d;
                    break;
                }
            }
        }
        __syncthreads();
    }
    if (threadIdx.x == 0) thr[b] = key2f(spre);
}

// ---------------------------------------------------------------------------
// K_NEGFIX: rare path only — SUBTRACT pt^2 of excluded negatives (tl < thr).
// ---------------------------------------------------------------------------
__global__ __launch_bounds__(256)
void k_negfix(const f4v* __restrict__ Tl, const f4v* __restrict__ Tm,
              const i4v* __restrict__ Ltk, const unsigned* __restrict__ fb,
              const float* __restrict__ thr, float* __restrict__ k1s) {
    const int b = blockIdx.y;
    if (fb[b]) return;
    const int tid = threadIdx.x;
    const long base4 = (long)b * HW4;
    const float tb = thr[b];
    float acc = 0.f;
#pragma unroll
    for (int j = 0; j < 4; ++j) {
        const int i4 = blockIdx.x * 1024 + j * 256 + tid;
        const f4v tl4 = Tl[base4 + i4];
        const f4v tm4 = Tm[base4 + i4];
        const i4v lt4 = Ltk[base4 + i4];
#pragma unroll
        for (int p = 0; p < 4; ++p) {
            bool tmb = tm4[p] > 0.5f;
            bool neg = lt4[p] <= 0;
            float tl = tl4[p];
            if (neg && tmb && tl < tb) {
                float pt = 1.f / (1.f + __expf(-tl));
                acc = fmaf(pt, pt, acc);
            }
        }
    }
    acc = wred64(acc);
    __shared__ float wa[4];
    if ((tid & 63) == 0) wa[tid >> 6] = acc;
    __syncthreads();
    if (tid == 0) {
        float s = wa[0] + wa[1] + wa[2] + wa[3];
        if (s != 0.f) atomicAdd(&k1s[b * NP + J_BTN], -s);
    }
}

// ---------------------------------------------------------------------------
// K6: final combine -> scalar loss.
// ---------------------------------------------------------------------------
__global__ __launch_bounds__(512)
void k6_final(const float* __restrict__ k1s, const float* __restrict__ kms,
              const float* __restrict__ slg, float* __restrict__ out) {
    const int tid = threadIdx.x;
    const int b = tid >> 6, lane = tid & 63;
    __shared__ float KmS[BATCH * 32];
    __shared__ float laS[BATCH], ldS[BATCH];
    if (tid < BATCH * 32) KmS[tid] = kms[tid];
    __syncthreads();
    const float* s1 = k1s + b * NP;

    float aggs = 0.f, aggc = 0.f;
    if (lane >= 1 && lane <= 8) {
        float ctv = s1[J_CNTT + lane - 1];
        float ckv = s1[J_CNTK + lane - 1];
        if (ctv > 0.f && ckv > 0.f) {
            aggs = slg[b * 8 + lane - 1] / fmaxf(ctv, 1.f);
            aggc = 1.f;
        }
    }
    float diss = 0.f, disc = 0.f;
    {
        int i = 1 + (lane >> 3), j = 1 + (lane & 7);
        if (i != j && s1[J_CNTK + i - 1] > 0.f && s1[J_CNTK + j - 1] > 0.f) {
            float d2 = 0.f;
#pragma unroll
            for (int c = 0; c < 4; ++c) {
                float df = KmS[b * 32 + (i - 1) * 4 + c] -
                           KmS[b * 32 + (j - 1) * 4 + c];
                d2 = fmaf(df, df, d2);
            }
            float kd = sqrtf(d2);
            float t = fmaxf(3.f - kd, 0.f);
            diss = logf(t * t + 1.f);
            disc = 1.f;
        }
    }
    aggs = wred64(aggs); aggc = wred64(aggc);
    diss = wred64(diss); disc = wred64(disc);
    if (lane == 0) {
        laS[b] = aggs / fmaxf(aggc, 1.f);
        ldS[b] = diss / fmaxf(disc, 1.f);
    }
    __syncthreads();
    if (tid == 0) {
        float Lt = 0.f, Lk = 0.f, La = 0.f, Ld = 0.f;
        for (int bb = 0; bb < BATCH; ++bb) {
            const float* a = k1s + bb * NP;
            Lk += 1.f - 2.f * a[J_AK] / ((a[J_BK] + 1e-6f) + (a[J_CK] + 1e-6f));
            float btv = a[J_BTP] + a[J_BTN];
            Lt += 1.f - 2.f * a[J_AT] / ((btv + 1e-6f) + (a[J_CPOS] + 1e-6f));
            La += laS[bb]; Ld += ldS[bb];
        }
        out[0] = Lt / BATCH + 0.5f * (Lk / BATCH) + 0.25f * (La / BATCH + Ld / BATCH);
    }
}

// ---------------------------------------------------------------------------
extern "C" void kernel_launch(void* const* d_in, const int* in_sizes, int n_in,
                              void* d_out, int out_size, void* d_ws, size_t ws_size,
                              hipStream_t stream) {
    (void)in_sizes; (void)n_in; (void)out_size; (void)ws_size;
    const f4v* Tl = (const f4v*)d_in[0];   // pre_text_logits
    const f4v* Kl = (const f4v*)d_in[1];   // pre_kernel_logits
    const f4v* Fv = (const f4v*)d_in[2];   // similarity_vector [B,C,H,W]
    const f4v* Tm = (const f4v*)d_in[5];   // train_mask
    const i4v* Ltk = (const i4v*)d_in[6];  // gt_text_key
    const i4v* Lkk = (const i4v*)d_in[7];  // gt_kernel_key
    float* out = (float*)d_out;

    // ws layout (4B units). memset region first: slg, minkeyinv, bar, ksum.
    float* slg = (float*)d_ws;                           // 64
    unsigned* minkeyinv = (unsigned*)(slg + 64);         // 8
    unsigned* bar = minkeyinv + BATCH;                   // 8 (1 used)
    float* ksum = (float*)(bar + BATCH);                 // 8*40 = 320
    float* thr = ksum + BATCH * 40;                      // 8
    unsigned* kval = (unsigned*)(thr + BATCH);           // 8
    unsigned* fb = kval + BATCH;                         // 8
    float* k1s = (float*)(fb + BATCH);                   // 8*56 = 448
    float* kms = k1s + BATCH * NP;                       // 8*32 = 256
    float* part = kms + BATCH * 32;                      // 8*16*100 = 12800

    hipMemsetAsync(d_ws, 0, (size_t)(64 + 8 + 8 + 320) * 4, stream);

    k1_fused<<<TOTB, 256, 0, stream>>>(Tl, Kl, Fv, Tm, Ltk, Lkk,
                                       ksum, part, minkeyinv, bar, slg);
    k1_reduce<<<BATCH, 256, 0, stream>>>(part, ksum, minkeyinv,
                                         k1s, kms, thr, kval, fb);
    k_rare<<<BATCH, 256, 0, stream>>>((const float*)d_in[0],
                                      (const int*)d_in[6], fb, kval, thr);
    k_negfix<<<dim3(NBLK, BATCH), 256, 0, stream>>>(Tl, Tm, Ltk, fb, thr, k1s);
    k6_final<<<1, 512, 0, stream>>>(k1s, kms, slg, out);
}

// Round 14
// 108.668 us; speedup vs baseline: 2.4835x; 1.0175x over previous
//
#include <hip/hip_runtime.h>
#include <math.h>

#define BATCH 8
#define HW_N 409600          // 640*640
#define HW4 (HW_N / 4)       // 102400
#define NBLK 400             // pixel-kernel blocks per batch (256 float4/block)

// k1s per-batch reduction slots
#define NP 48
#define J_AK   0             // kernel dice: sum pk*gk*km
#define J_BK   1             //              sum pk*pk*km
#define J_CK   2             //              sum gk*km
#define J_AT   3             // text dice:   sum pt over pos&tm
#define J_BTP  4             //              sum pt^2 over pos&tm
#define J_BTN  5             //              sum pt^2 over ALL neg&tm (negfix subtracts)
#define J_CPOS 6             // count(pos & tm)
#define J_CNEG 7             // count(!pos)
#define J_CNTK 8             // +(s-1), s=1..8
#define J_SUMK 16            // +(s-1)*4+c  (32)

typedef float f4v __attribute__((ext_vector_type(4)));
typedef int   i4v __attribute__((ext_vector_type(4)));

__device__ __forceinline__ unsigned f2key(float x) {
    unsigned u = __float_as_uint(x);
    return (u & 0x80000000u) ? ~u : (u | 0x80000000u);
}
__device__ __forceinline__ float key2f(unsigned k) {
    unsigned u = (k & 0x80000000u) ? (k & 0x7fffffffu) : ~k;
    return __uint_as_float(u);
}
__device__ __forceinline__ float wred64(float v) {
#pragma unroll
    for (int o = 32; o > 0; o >>= 1) v += __shfl_xor(v, o, 64);
    return v;
}
__device__ __forceinline__ float wredmin64(float v) {
#pragma unroll
    for (int o = 32; o > 0; o >>= 1) v = fminf(v, __shfl_xor(v, o, 64));
    return v;
}

// ---------------------------------------------------------------------------
// K1: heavy pass. 1 float4/thread, 3200 short blocks (max TLP), all 10 loads
// issued up front and pinned (batched issue, one wait). Normal cached loads.
// Per-block partials -> part[] (contention-free). sum_k/cnt_k via LDS atomics.
// ---------------------------------------------------------------------------
__global__ __launch_bounds__(256)
void k1_main(const f4v* __restrict__ Tl, const f4v* __restrict__ Kl,
             const f4v* __restrict__ Fv, const f4v* __restrict__ Tm,
             const i4v* __restrict__ Ltk, const i4v* __restrict__ Lkk,
             float* __restrict__ part, unsigned* __restrict__ pk8,
             unsigned* __restrict__ minkeyinv) {
    const int b = blockIdx.y;
    const int tid = threadIdx.x;
    const int wid = tid >> 6, lane = tid & 63;
    const long base4 = (long)b * HW4;
    const long f04 = (long)b * 4 * HW4;

    __shared__ float sK[32];
    __shared__ unsigned cKs[8];
    __shared__ float wacc[4][8];
    __shared__ float wmin[4];
    if (tid < 32) sK[tid] = 0.f;
    else if (tid < 40) cKs[tid - 32] = 0u;
    __syncthreads();

    const int i4 = blockIdx.x * 256 + tid;

    // ---- issue ALL 10 loads, then pin (batched issue, one wait) ----
    const f4v tl4 = Tl[base4 + i4];
    const f4v kl4 = Kl[base4 + i4];
    const f4v tm4 = Tm[base4 + i4];
    const i4v lt4 = Ltk[base4 + i4];
    const i4v lk4 = Lkk[base4 + i4];
    const f4v F0v = Fv[f04 + i4];
    const f4v F1v = Fv[f04 + HW4 + i4];
    const f4v F2v = Fv[f04 + 2 * HW4 + i4];
    const f4v F3v = Fv[f04 + 3 * HW4 + i4];
    asm volatile("" ::
        "v"(tl4.x), "v"(kl4.x), "v"(tm4.x), "v"(lt4.x), "v"(lk4.x),
        "v"(F0v.x), "v"(F1v.x), "v"(F2v.x), "v"(F3v.x));

    float r0 = 0.f, r1 = 0.f, r2 = 0.f, r3 = 0.f, r4 = 0.f, r5 = 0.f;
    float cpos = 0.f, cneg = 0.f;
    float vmin = INFINITY;
    unsigned pkw = 0u;

#pragma unroll
    for (int p = 0; p < 4; ++p) {
        float tl = tl4[p], kl = kl4[p], m = tm4[p];
        int ltk = lt4[p], lkk = lk4[p];
        bool tmb = m > 0.5f;
        bool selt = tl > 0.f;      // sigmoid(x)>0.5 <=> x>0
        bool selk = kl > 0.f;
        bool pos = ltk > 0;        // gt_text == (gt_text_key > 0)
        float gkf = (lkk > 0) ? 1.f : 0.f;
        float km = (selt && tmb) ? 1.f : 0.f;
        float pkv = 1.f / (1.f + __expf(-kl));
        float ptv = 1.f / (1.f + __expf(-tl));
        r0 = fmaf(pkv * gkf, km, r0);
        r1 = fmaf(pkv * pkv, km, r1);
        r2 = fmaf(gkf, km, r2);
        float ptm = (pos && tmb) ? 1.f : 0.f;
        float ntm = (!pos && tmb) ? 1.f : 0.f;
        r3 = fmaf(ptv, ptm, r3);
        r4 = fmaf(ptv * ptv, ptm, r4);
        r5 = fmaf(ptv * ptv, ntm, r5);
        cpos += ptm;
        cneg += pos ? 0.f : 1.f;
        vmin = fminf(vmin, pos ? INFINITY : tl);
        int lk = (selk && tmb) ? lkk : 0;
        if (lk > 0) {
            atomicAdd(&sK[(lk - 1) * 4 + 0], F0v[p]);
            atomicAdd(&sK[(lk - 1) * 4 + 1], F1v[p]);
            atomicAdd(&sK[(lk - 1) * 4 + 2], F2v[p]);
            atomicAdd(&sK[(lk - 1) * 4 + 3], F3v[p]);
            atomicAdd(&cKs[lk - 1], 1u);
        }
        pkw |= ((tmb ? 1u : 0u) | (selt ? 2u : 0u) | ((unsigned)ltk << 2)) << (8 * p);
    }
    pk8[base4 + i4] = pkw;

    r0 = wred64(r0); r1 = wred64(r1); r2 = wred64(r2);
    r3 = wred64(r3); r4 = wred64(r4); r5 = wred64(r5);
    cpos = wred64(cpos); cneg = wred64(cneg);
    vmin = wredmin64(vmin);
    if (lane == 0) {
        wacc[wid][0] = r0; wacc[wid][1] = r1; wacc[wid][2] = r2;
        wacc[wid][3] = r3; wacc[wid][4] = r4; wacc[wid][5] = r5;
        wacc[wid][6] = cpos; wacc[wid][7] = cneg;
        wmin[wid] = vmin;
    }
    __syncthreads();
    if (tid < NP) {
        float v;
        if (tid < 8)       v = wacc[0][tid] + wacc[1][tid] + wacc[2][tid] + wacc[3][tid];
        else if (tid < 16) v = (float)cKs[tid - 8];
        else               v = sK[tid - 16];
        part[((size_t)b * NP + tid) * NBLK + blockIdx.x] = v;
    }
    if (tid == 48) {
        float mn = fminf(fminf(wmin[0], wmin[1]), fminf(wmin[2], wmin[3]));
        if (mn < INFINITY) atomicMax(&minkeyinv[b], ~f2key(mn));
    }
}

// ---------------------------------------------------------------------------
// K1R: reduce per-block partials, OHEM decision, kernel means.
// ---------------------------------------------------------------------------
__global__ __launch_bounds__(256)
void k1_reduce(const float* __restrict__ part, const unsigned* __restrict__ minkeyinv,
               float* __restrict__ k1s, float* __restrict__ kms,
               float* __restrict__ thr, unsigned* __restrict__ kval,
               unsigned* __restrict__ fb) {
    const int b = blockIdx.x;
    const int tid = threadIdx.x, wid = tid >> 6, lane = tid & 63;
    __shared__ float ss[NP];
    for (int j = wid; j < NP; j += 4) {
        const float* p = part + ((size_t)b * NP + j) * NBLK;
        float v = 0.f;
        for (int i = lane; i < NBLK; i += 64) v += p[i];
        v = wred64(v);
        if (lane == 0) ss[j] = v;
    }
    __syncthreads();
    if (tid == 0) {
        unsigned pos = (unsigned)(ss[J_CPOS] + 0.5f);
        unsigned neg = (unsigned)(ss[J_CNEG] + 0.5f);
        unsigned k = min(3u * pos, neg);
        kval[b] = k;
        if (pos == 0u || k == 0u) { thr[b] = -INFINITY; fb[b] = 1u; }
        else if (k == neg)        { thr[b] = key2f(~minkeyinv[b]); fb[b] = 1u; }
        else                      { fb[b] = 0u; }   // rare: radix path
    }
    if (tid < NP) k1s[b * NP + tid] = ss[tid];
    if (tid >= 64 && tid < 96) {
        int t = tid - 64, s = t >> 2;
        kms[b * 32 + t] = ss[J_SUMK + t] / fmaxf(ss[J_CNTK + s], 1.f);
    }
}

// ---------------------------------------------------------------------------
// K_RARE: exact k-th-largest negative logit via 4-pass radix select.
// Early-exits in the common (fb=1) case.
// ---------------------------------------------------------------------------
__global__ __launch_bounds__(256)
void k_rare(const float* __restrict__ Tl, const unsigned char* __restrict__ pk8b,
            const unsigned* __restrict__ fb, const unsigned* __restrict__ kval,
            float* __restrict__ thr) {
    const int b = blockIdx.x;
    if (fb[b]) return;
    __shared__ unsigned hist[256];
    __shared__ unsigned sj, spre;
    const long base = (long)b * HW_N;
    if (threadIdx.x == 0) { sj = kval[b]; spre = 0u; }
    __syncthreads();
    for (int pass = 0; pass < 4; ++pass) {
        const int shift = 24 - 8 * pass;
        hist[threadIdx.x] = 0u;
        __syncthreads();
        const unsigned pref = spre;
        for (int i = threadIdx.x; i < HW_N; i += 256) {
            if ((pk8b[base + i] >> 2) != 0u) continue;   // pos pixel
            unsigned key = f2key(Tl[base + i]);
            if (pass == 0 || (key >> (shift + 8)) == pref)
                atomicAdd(&hist[(key >> shift) & 0xFFu], 1u);
        }
        __syncthreads();
        if (threadIdx.x == 0) {
            unsigned j = sj, cum = 0;
            for (int d = 255; d >= 0; --d) {
                cum += hist[d];
                if (cum >= j) {
                    sj = j - (cum - hist[d]);
                    spre = (pref << 8) | (unsigned)d;
                    break;
                }
            }
        }
        __syncthreads();
    }
    if (threadIdx.x == 0) thr[b] = key2f(spre);
}

// ---------------------------------------------------------------------------
// K_NEGFIX: rare path only — SUBTRACT pt^2 of excluded negatives (tl < thr).
// ---------------------------------------------------------------------------
__global__ __launch_bounds__(256)
void k_negfix(const f4v* __restrict__ Tl, const unsigned* __restrict__ pk8,
              const unsigned* __restrict__ fb, const float* __restrict__ thr,
              float* __restrict__ k1s) {
    const int b = blockIdx.y;
    if (fb[b]) return;
    const int tid = threadIdx.x;
    const long base4 = (long)b * HW4;
    const float tb = thr[b];
    float acc = 0.f;
#pragma unroll
    for (int j = 0; j < 4; ++j) {
        const int i4 = blockIdx.x * 1024 + j * 256 + tid;
        const f4v tl4 = Tl[base4 + i4];
        const unsigned pkw = pk8[base4 + i4];
#pragma unroll
        for (int p = 0; p < 4; ++p) {
            unsigned byte = (pkw >> (8 * p)) & 0xFFu;
            bool tmb = byte & 1u;
            bool neg = (byte >> 2) == 0u;
            float tl = tl4[p];
            if (neg && tmb && tl < tb) {
                float pt = 1.f / (1.f + __expf(-tl));
                acc = fmaf(pt, pt, acc);
            }
        }
    }
    acc = wred64(acc);
    __shared__ float wa[4];
    if ((tid & 63) == 0) wa[tid >> 6] = acc;
    __syncthreads();
    if (tid == 0) {
        float s = wa[0] + wa[1] + wa[2] + wa[3];
        if (s != 0.f) atomicAdd(&k1s[b * NP + J_BTN], -s);
    }
}

// ---------------------------------------------------------------------------
// K5: aggregation pass — Fv + packed plane, 1 float4/thread, pinned batch;
// register accumulators for sum_l and cnt_t; 16 global atomics per block.
// ---------------------------------------------------------------------------
__global__ __launch_bounds__(256)
void k5_agg(const unsigned* __restrict__ pk8, const f4v* __restrict__ Fv,
            const float* __restrict__ kms, float* __restrict__ slg) {
    const int b = blockIdx.y;
    const int tid = threadIdx.x, wid = tid >> 6, lane = tid & 63;
    __shared__ float Kml[32];
    __shared__ float wacc[4][16];
    if (tid < 32) Kml[tid] = kms[b * 32 + tid];
    __syncthreads();
    const long base4 = (long)b * HW4;
    const long f04 = (long)b * 4 * HW4;
    const int i4 = blockIdx.x * 256 + tid;

    // ---- issue ALL 5 loads, then pin ----
    const unsigned pkw = pk8[base4 + i4];
    const f4v F0v = Fv[f04 + i4];
    const f4v F1v = Fv[f04 + HW4 + i4];
    const f4v F2v = Fv[f04 + 2 * HW4 + i4];
    const f4v F3v = Fv[f04 + 3 * HW4 + i4];
    asm volatile("" ::
        "v"(pkw), "v"(F0v.x), "v"(F1v.x), "v"(F2v.x), "v"(F3v.x));

    float sl8[8] = {0.f, 0.f, 0.f, 0.f, 0.f, 0.f, 0.f, 0.f};
    float ct8[8] = {0.f, 0.f, 0.f, 0.f, 0.f, 0.f, 0.f, 0.f};

#pragma unroll
    for (int p = 0; p < 4; ++p) {
        unsigned byte = (pkw >> (8 * p)) & 0xFFu;
        int lt = ((byte & 3u) == 3u) ? (int)(byte >> 2) : 0;
        int kb = (lt > 0 ? lt - 1 : 0) * 4;
        float d0 = F0v[p] - Kml[kb + 0];
        float d1 = F1v[p] - Kml[kb + 1];
        float d2 = F2v[p] - Kml[kb + 2];
        float d3 = F3v[p] - Kml[kb + 3];
        float d = sqrtf(fmaf(d0, d0, fmaf(d1, d1, fmaf(d2, d2, d3 * d3))));
        float t = fmaxf(d - 0.5f, 0.f);
        float pl = __logf(fmaf(t, t, 1.f));
#pragma unroll
        for (int s = 1; s <= 8; ++s) {
            float e = (lt == s) ? 1.f : 0.f;
            sl8[s - 1] = fmaf(e, pl, sl8[s - 1]);
            ct8[s - 1] += e;
        }
    }

#pragma unroll
    for (int j = 0; j < 8; ++j) { sl8[j] = wred64(sl8[j]); ct8[j] = wred64(ct8[j]); }
    if (lane == 0) {
#pragma unroll
        for (int j = 0; j < 8; ++j) { wacc[wid][j] = sl8[j]; wacc[wid][8 + j] = ct8[j]; }
    }
    __syncthreads();
    if (tid < 16) {
        float v = wacc[0][tid] + wacc[1][tid] + wacc[2][tid] + wacc[3][tid];
        if (v != 0.f) atomicAdd(&slg[b * 16 + tid], v);
    }
}

// ---------------------------------------------------------------------------
// K6: final combine -> scalar loss.
// ---------------------------------------------------------------------------
__global__ __launch_bounds__(512)
void k6_final(const float* __restrict__ k1s, const float* __restrict__ kms,
              const float* __restrict__ slg, float* __restrict__ out) {
    const int tid = threadIdx.x;
    const int b = tid >> 6, lane = tid & 63;
    __shared__ float KmS[BATCH * 32];
    __shared__ float laS[BATCH], ldS[BATCH];
    if (tid < BATCH * 32) KmS[tid] = kms[tid];
    __syncthreads();
    const float* s1 = k1s + b * NP;

    float aggs = 0.f, aggc = 0.f;
    if (lane >= 1 && lane <= 8) {
        float ctv = slg[b * 16 + 8 + lane - 1];
        float ckv = s1[J_CNTK + lane - 1];
        if (ctv > 0.f && ckv > 0.f) {
            aggs = slg[b * 16 + lane - 1] / fmaxf(ctv, 1.f);
            aggc = 1.f;
        }
    }
    float diss = 0.f, disc = 0.f;
    {
        int i = 1 + (lane >> 3), j = 1 + (lane & 7);
        if (i != j && s1[J_CNTK + i - 1] > 0.f && s1[J_CNTK + j - 1] > 0.f) {
            float d2 = 0.f;
#pragma unroll
            for (int c = 0; c < 4; ++c) {
                float df = KmS[b * 32 + (i - 1) * 4 + c] -
                           KmS[b * 32 + (j - 1) * 4 + c];
                d2 = fmaf(df, df, d2);
            }
            float kd = sqrtf(d2);
            float t = fmaxf(3.f - kd, 0.f);
            diss = logf(t * t + 1.f);
            disc = 1.f;
        }
    }
    aggs = wred64(aggs); aggc = wred64(aggc);
    diss = wred64(diss); disc = wred64(disc);
    if (lane == 0) {
        laS[b] = aggs / fmaxf(aggc, 1.f);
        ldS[b] = diss / fmaxf(disc, 1.f);
    }
    __syncthreads();
    if (tid == 0) {
        float Lt = 0.f, Lk = 0.f, La = 0.f, Ld = 0.f;
        for (int bb = 0; bb < BATCH; ++bb) {
            const float* a = k1s + bb * NP;
            Lk += 1.f - 2.f * a[J_AK] / ((a[J_BK] + 1e-6f) + (a[J_CK] + 1e-6f));
            float btv = a[J_BTP] + a[J_BTN];
            Lt += 1.f - 2.f * a[J_AT] / ((btv + 1e-6f) + (a[J_CPOS] + 1e-6f));
            La += laS[bb]; Ld += ldS[bb];
        }
        out[0] = Lt / BATCH + 0.5f * (Lk / BATCH) + 0.25f * (La / BATCH + Ld / BATCH);
    }
}

// ---------------------------------------------------------------------------
extern "C" void kernel_launch(void* const* d_in, const int* in_sizes, int n_in,
                              void* d_out, int out_size, void* d_ws, size_t ws_size,
                              hipStream_t stream) {
    (void)in_sizes; (void)n_in; (void)out_size; (void)ws_size;
    const f4v* Tl = (const f4v*)d_in[0];   // pre_text_logits
    const f4v* Kl = (const f4v*)d_in[1];   // pre_kernel_logits
    const f4v* Fv = (const f4v*)d_in[2];   // similarity_vector [B,C,H,W]
    const f4v* Tm = (const f4v*)d_in[5];   // train_mask
    const i4v* Ltk = (const i4v*)d_in[6];  // gt_text_key
    const i4v* Lkk = (const i4v*)d_in[7];  // gt_kernel_key
    float* out = (float*)d_out;

    // ws layout (4B units). memset region first: k1s, slg, minkeyinv.
    float* k1s = (float*)d_ws;                           // 8*48 = 384
    float* slg = k1s + BATCH * NP;                       // 8*16 = 128
    unsigned* minkeyinv = (unsigned*)(slg + BATCH * 16); // 8
    float* thr = (float*)(minkeyinv + BATCH);            // 8
    unsigned* kval = (unsigned*)(thr + BATCH);           // 8
    unsigned* fb = kval + BATCH;                         // 8
    float* kms = (float*)(fb + BATCH);                   // 8*32 = 256
    float* part = kms + BATCH * 32;                      // 8*48*400 = 153600
    unsigned* pk8 = (unsigned*)(part + (size_t)BATCH * NP * NBLK); // 8*HW4

    hipMemsetAsync(d_ws, 0, (size_t)(BATCH * NP + BATCH * 16 + BATCH) * 4, stream);

    dim3 g(NBLK, BATCH);          // (400, 8): one float4 per thread
    k1_main<<<g, 256, 0, stream>>>(Tl, Kl, Fv, Tm, Ltk, Lkk, part, pk8, minkeyinv);
    k1_reduce<<<BATCH, 256, 0, stream>>>(part, minkeyinv, k1s, kms, thr, kval, fb);
    k_rare<<<BATCH, 256, 0, stream>>>((const float*)d_in[0],
                                      (const unsigned char*)pk8, fb, kval, thr);
    k_negfix<<<dim3(100, BATCH), 256, 0, stream>>>(Tl, pk8, fb, thr, k1s);
    k5_agg<<<g, 256, 0, stream>>>(pk8, Fv, kms, slg);
    k6_final<<<1, 512, 0, stream>>>(k1s, kms, slg, out);
}

// Round 15
// 95.785 us; speedup vs baseline: 2.8175x; 1.1345x over previous
//
#include <hip/hip_runtime.h>
#include <math.h>

#define BATCH 8
#define HW_N 409600          // 640*640
#define HW4 (HW_N / 4)       // 102400
#define NBLK 200             // pixel-kernel blocks per batch (512 float4/block)

// k1s per-batch reduction slots
#define NP 48
#define J_AK   0             // kernel dice: sum pk*gk*km
#define J_BK   1             //              sum pk*pk*km
#define J_CK   2             //              sum gk*km
#define J_AT   3             // text dice:   sum pt over pos&tm
#define J_BTP  4             //              sum pt^2 over pos&tm
#define J_BTN  5             //              sum pt^2 over ALL neg&tm (negfix subtracts)
#define J_CPOS 6             // count(pos & tm)
#define J_CNEG 7             // count(!pos)
#define J_CNTK 8             // +(s-1), s=1..8
#define J_SUMK 16            // +(s-1)*4+c  (32)

typedef float f4v __attribute__((ext_vector_type(4)));
typedef int   i4v __attribute__((ext_vector_type(4)));

__device__ __forceinline__ unsigned f2key(float x) {
    unsigned u = __float_as_uint(x);
    return (u & 0x80000000u) ? ~u : (u | 0x80000000u);
}
__device__ __forceinline__ float key2f(unsigned k) {
    unsigned u = (k & 0x80000000u) ? (k & 0x7fffffffu) : ~k;
    return __uint_as_float(u);
}
__device__ __forceinline__ float wred64(float v) {
#pragma unroll
    for (int o = 32; o > 0; o >>= 1) v += __shfl_xor(v, o, 64);
    return v;
}
__device__ __forceinline__ float wredmin64(float v) {
#pragma unroll
    for (int o = 32; o > 0; o >>= 1) v = fminf(v, __shfl_xor(v, o, 64));
    return v;
}

// ---------------------------------------------------------------------------
// K1: heavy pass (proven 42µs config: 2 float4/thread, 20-load pinned batch).
// Per-block partials -> part[] (contention-free); sum_k/cnt_k via LDS atomics.
// ---------------------------------------------------------------------------
__global__ __launch_bounds__(256)
void k1_main(const f4v* __restrict__ Tl, const f4v* __restrict__ Kl,
             const f4v* __restrict__ Fv, const f4v* __restrict__ Tm,
             const i4v* __restrict__ Ltk, const i4v* __restrict__ Lkk,
             float* __restrict__ part, unsigned* __restrict__ pk8,
             unsigned* __restrict__ minkeyinv) {
    const int b = blockIdx.y;
    const int tid = threadIdx.x;
    const int wid = tid >> 6, lane = tid & 63;
    const long base4 = (long)b * HW4;
    const long f04 = (long)b * 4 * HW4;

    __shared__ float sK[32];
    __shared__ unsigned cKs[8];
    __shared__ float wacc[4][8];
    __shared__ float wmin[4];
    if (tid < 32) sK[tid] = 0.f;
    else if (tid < 40) cKs[tid - 32] = 0u;
    __syncthreads();

    const int i0 = blockIdx.x * 512 + tid;
    const int i1 = i0 + 256;

    // ---- issue ALL 20 loads, then pin (batched issue, one wait) ----
    const f4v tlA = Tl[base4 + i0],  tlB = Tl[base4 + i1];
    const f4v klA = Kl[base4 + i0],  klB = Kl[base4 + i1];
    const f4v tmA = Tm[base4 + i0],  tmB = Tm[base4 + i1];
    const i4v ltA = Ltk[base4 + i0], ltB = Ltk[base4 + i1];
    const i4v lkA = Lkk[base4 + i0], lkB = Lkk[base4 + i1];
    const f4v f0A = Fv[f04 + i0],            f0B = Fv[f04 + i1];
    const f4v f1A = Fv[f04 + HW4 + i0],      f1B = Fv[f04 + HW4 + i1];
    const f4v f2A = Fv[f04 + 2 * HW4 + i0],  f2B = Fv[f04 + 2 * HW4 + i1];
    const f4v f3A = Fv[f04 + 3 * HW4 + i0],  f3B = Fv[f04 + 3 * HW4 + i1];
    asm volatile("" ::
        "v"(tlA.x), "v"(tlB.x), "v"(klA.x), "v"(klB.x), "v"(tmA.x), "v"(tmB.x),
        "v"(f0A.x), "v"(f0B.x), "v"(f1A.x), "v"(f1B.x),
        "v"(f2A.x), "v"(f2B.x), "v"(f3A.x), "v"(f3B.x),
        "v"(ltA.x), "v"(ltB.x), "v"(lkA.x), "v"(lkB.x));

    float r0 = 0.f, r1 = 0.f, r2 = 0.f, r3 = 0.f, r4 = 0.f, r5 = 0.f;
    float cpos = 0.f, cneg = 0.f;
    float vmin = INFINITY;

#pragma unroll
    for (int it = 0; it < 2; ++it) {
        const f4v tl4 = it ? tlB : tlA;
        const f4v kl4 = it ? klB : klA;
        const f4v tm4 = it ? tmB : tmA;
        const i4v lt4 = it ? ltB : ltA;
        const i4v lk4 = it ? lkB : lkA;
        const f4v F0v = it ? f0B : f0A;
        const f4v F1v = it ? f1B : f1A;
        const f4v F2v = it ? f2B : f2A;
        const f4v F3v = it ? f3B : f3A;
        unsigned pkw = 0u;
#pragma unroll
        for (int p = 0; p < 4; ++p) {
            float tl = tl4[p], kl = kl4[p], m = tm4[p];
            int ltk = lt4[p], lkk = lk4[p];
            bool tmb = m > 0.5f;
            bool selt = tl > 0.f;      // sigmoid(x)>0.5 <=> x>0
            bool selk = kl > 0.f;
            bool pos = ltk > 0;        // gt_text == (gt_text_key > 0)
            float gkf = (lkk > 0) ? 1.f : 0.f;
            float km = (selt && tmb) ? 1.f : 0.f;
            float pkv = 1.f / (1.f + __expf(-kl));
            float ptv = 1.f / (1.f + __expf(-tl));
            r0 = fmaf(pkv * gkf, km, r0);
            r1 = fmaf(pkv * pkv, km, r1);
            r2 = fmaf(gkf, km, r2);
            float ptm = (pos && tmb) ? 1.f : 0.f;
            float ntm = (!pos && tmb) ? 1.f : 0.f;
            r3 = fmaf(ptv, ptm, r3);
            r4 = fmaf(ptv * ptv, ptm, r4);
            r5 = fmaf(ptv * ptv, ntm, r5);
            cpos += ptm;
            cneg += pos ? 0.f : 1.f;
            vmin = fminf(vmin, pos ? INFINITY : tl);
            int lk = (selk && tmb) ? lkk : 0;
            if (lk > 0) {
                atomicAdd(&sK[(lk - 1) * 4 + 0], F0v[p]);
                atomicAdd(&sK[(lk - 1) * 4 + 1], F1v[p]);
                atomicAdd(&sK[(lk - 1) * 4 + 2], F2v[p]);
                atomicAdd(&sK[(lk - 1) * 4 + 3], F3v[p]);
                atomicAdd(&cKs[lk - 1], 1u);
            }
            pkw |= ((tmb ? 1u : 0u) | (selt ? 2u : 0u) | ((unsigned)ltk << 2)) << (8 * p);
        }
        pk8[base4 + (it ? i1 : i0)] = pkw;
    }

    r0 = wred64(r0); r1 = wred64(r1); r2 = wred64(r2);
    r3 = wred64(r3); r4 = wred64(r4); r5 = wred64(r5);
    cpos = wred64(cpos); cneg = wred64(cneg);
    vmin = wredmin64(vmin);
    if (lane == 0) {
        wacc[wid][0] = r0; wacc[wid][1] = r1; wacc[wid][2] = r2;
        wacc[wid][3] = r3; wacc[wid][4] = r4; wacc[wid][5] = r5;
        wacc[wid][6] = cpos; wacc[wid][7] = cneg;
        wmin[wid] = vmin;
    }
    __syncthreads();
    if (tid < NP) {
        float v;
        if (tid < 8)       v = wacc[0][tid] + wacc[1][tid] + wacc[2][tid] + wacc[3][tid];
        else if (tid < 16) v = (float)cKs[tid - 8];
        else               v = sK[tid - 16];
        part[((size_t)b * NP + tid) * NBLK + blockIdx.x] = v;
    }
    if (tid == 48) {
        float mn = fminf(fminf(wmin[0], wmin[1]), fminf(wmin[2], wmin[3]));
        if (mn < INFINITY) atomicMax(&minkeyinv[b], ~f2key(mn));
    }
}

// ---------------------------------------------------------------------------
// K1R: reduce per-block partials, OHEM decision, kernel means, AND (rare
// path) the exact radix select inline — saves one kernel launch.
// ---------------------------------------------------------------------------
__global__ __launch_bounds__(256)
void k1_reduce(const float* __restrict__ part, const unsigned* __restrict__ minkeyinv,
               const float* __restrict__ Tl, const unsigned char* __restrict__ pk8b,
               float* __restrict__ k1s, float* __restrict__ kms,
               float* __restrict__ thr, unsigned* __restrict__ fb) {
    const int b = blockIdx.x;
    const int tid = threadIdx.x, wid = tid >> 6, lane = tid & 63;
    __shared__ float ss[NP];
    __shared__ unsigned sfb, sj, spre;
    __shared__ unsigned hist[256];
    for (int j = wid; j < NP; j += 4) {
        const float* p = part + ((size_t)b * NP + j) * NBLK;
        float v = 0.f;
        for (int i = lane; i < NBLK; i += 64) v += p[i];
        v = wred64(v);
        if (lane == 0) ss[j] = v;
    }
    __syncthreads();
    if (tid == 0) {
        unsigned pos = (unsigned)(ss[J_CPOS] + 0.5f);
        unsigned neg = (unsigned)(ss[J_CNEG] + 0.5f);
        unsigned k = min(3u * pos, neg);
        unsigned f;
        if (pos == 0u || k == 0u) { thr[b] = -INFINITY; f = 1u; }
        else if (k == neg)        { thr[b] = key2f(~minkeyinv[b]); f = 1u; }
        else                      { f = 0u; sj = k; spre = 0u; }
        fb[b] = f; sfb = f;
    }
    if (tid < NP) k1s[b * NP + tid] = ss[tid];
    if (tid >= 64 && tid < 96) {
        int t = tid - 64, s = t >> 2;
        kms[b * 32 + t] = ss[J_SUMK + t] / fmaxf(ss[J_CNTK + s], 1.f);
    }
    __syncthreads();
    if (sfb) return;

    // ---- rare path: exact k-th-largest negative logit, 4-pass radix ----
    const long base = (long)b * HW_N;
    for (int pass = 0; pass < 4; ++pass) {
        const int shift = 24 - 8 * pass;
        hist[tid] = 0u;
        __syncthreads();
        const unsigned pref = spre;
        for (int i = tid; i < HW_N; i += 256) {
            if ((pk8b[base + i] >> 2) != 0u) continue;   // pos pixel
            unsigned key = f2key(Tl[base + i]);
            if (pass == 0 || (key >> (shift + 8)) == pref)
                atomicAdd(&hist[(key >> shift) & 0xFFu], 1u);
        }
        __syncthreads();
        if (tid == 0) {
            unsigned j = sj, cum = 0;
            for (int d = 255; d >= 0; --d) {
                cum += hist[d];
                if (cum >= j) {
                    sj = j - (cum - hist[d]);
                    spre = (spre << 8) | (unsigned)d;
                    break;
                }
            }
        }
        __syncthreads();
    }
    if (tid == 0) thr[b] = key2f(spre);
}

// ---------------------------------------------------------------------------
// K_NEGFIX: rare path only — SUBTRACT pt^2 of excluded negatives (tl < thr).
// ---------------------------------------------------------------------------
__global__ __launch_bounds__(256)
void k_negfix(const f4v* __restrict__ Tl, const unsigned* __restrict__ pk8,
              const unsigned* __restrict__ fb, const float* __restrict__ thr,
              float* __restrict__ k1s) {
    const int b = blockIdx.y;
    if (fb[b]) return;
    const int tid = threadIdx.x;
    const long base4 = (long)b * HW4;
    const float tb = thr[b];
    float acc = 0.f;
#pragma unroll
    for (int j = 0; j < 4; ++j) {
        const int i4 = blockIdx.x * 1024 + j * 256 + tid;
        const f4v tl4 = Tl[base4 + i4];
        const unsigned pkw = pk8[base4 + i4];
#pragma unroll
        for (int p = 0; p < 4; ++p) {
            unsigned byte = (pkw >> (8 * p)) & 0xFFu;
            bool tmb = byte & 1u;
            bool neg = (byte >> 2) == 0u;
            float tl = tl4[p];
            if (neg && tmb && tl < tb) {
                float pt = 1.f / (1.f + __expf(-tl));
                acc = fmaf(pt, pt, acc);
            }
        }
    }
    acc = wred64(acc);
    __shared__ float wa[4];
    if ((tid & 63) == 0) wa[tid >> 6] = acc;
    __syncthreads();
    if (tid == 0) {
        float s = wa[0] + wa[1] + wa[2] + wa[3];
        if (s != 0.f) atomicAdd(&k1s[b * NP + J_BTN], -s);
    }
}

// ---------------------------------------------------------------------------
// K5: aggregation pass — Fv + packed plane, 2 float4/thread, pinned batch;
// register accumulators; contention-free part5[] output (no global atomics).
// ---------------------------------------------------------------------------
__global__ __launch_bounds__(256)
void k5_agg(const unsigned* __restrict__ pk8, const f4v* __restrict__ Fv,
            const float* __restrict__ kms, float* __restrict__ part5) {
    const int b = blockIdx.y;
    const int tid = threadIdx.x, wid = tid >> 6, lane = tid & 63;
    __shared__ float Kml[32];
    __shared__ float wacc[4][16];
    if (tid < 32) Kml[tid] = kms[b * 32 + tid];
    __syncthreads();
    const long base4 = (long)b * HW4;
    const long f04 = (long)b * 4 * HW4;
    const int i0 = blockIdx.x * 512 + tid;
    const int i1 = i0 + 256;

    // ---- issue ALL 10 loads, then pin ----
    const unsigned pkwA = pk8[base4 + i0], pkwB = pk8[base4 + i1];
    const f4v f0A = Fv[f04 + i0],           f0B = Fv[f04 + i1];
    const f4v f1A = Fv[f04 + HW4 + i0],     f1B = Fv[f04 + HW4 + i1];
    const f4v f2A = Fv[f04 + 2 * HW4 + i0], f2B = Fv[f04 + 2 * HW4 + i1];
    const f4v f3A = Fv[f04 + 3 * HW4 + i0], f3B = Fv[f04 + 3 * HW4 + i1];
    asm volatile("" ::
        "v"(pkwA), "v"(pkwB),
        "v"(f0A.x), "v"(f0B.x), "v"(f1A.x), "v"(f1B.x),
        "v"(f2A.x), "v"(f2B.x), "v"(f3A.x), "v"(f3B.x));

    float sl8[8] = {0.f, 0.f, 0.f, 0.f, 0.f, 0.f, 0.f, 0.f};
    float ct8[8] = {0.f, 0.f, 0.f, 0.f, 0.f, 0.f, 0.f, 0.f};

#pragma unroll
    for (int it = 0; it < 2; ++it) {
        const unsigned pkw = it ? pkwB : pkwA;
        const f4v F0v = it ? f0B : f0A;
        const f4v F1v = it ? f1B : f1A;
        const f4v F2v = it ? f2B : f2A;
        const f4v F3v = it ? f3B : f3A;
#pragma unroll
        for (int p = 0; p < 4; ++p) {
            unsigned byte = (pkw >> (8 * p)) & 0xFFu;
            int lt = ((byte & 3u) == 3u) ? (int)(byte >> 2) : 0;
            int kb = (lt > 0 ? lt - 1 : 0) * 4;
            float d0 = F0v[p] - Kml[kb + 0];
            float d1 = F1v[p] - Kml[kb + 1];
            float d2 = F2v[p] - Kml[kb + 2];
            float d3 = F3v[p] - Kml[kb + 3];
            float d = sqrtf(fmaf(d0, d0, fmaf(d1, d1, fmaf(d2, d2, d3 * d3))));
            float t = fmaxf(d - 0.5f, 0.f);
            float pl = __logf(fmaf(t, t, 1.f));
#pragma unroll
            for (int s = 1; s <= 8; ++s) {
                float e = (lt == s) ? 1.f : 0.f;
                sl8[s - 1] = fmaf(e, pl, sl8[s - 1]);
                ct8[s - 1] += e;
            }
        }
    }

#pragma unroll
    for (int j = 0; j < 8; ++j) { sl8[j] = wred64(sl8[j]); ct8[j] = wred64(ct8[j]); }
    if (lane == 0) {
#pragma unroll
        for (int j = 0; j < 8; ++j) { wacc[wid][j] = sl8[j]; wacc[wid][8 + j] = ct8[j]; }
    }
    __syncthreads();
    if (tid < 16) {
        float v = wacc[0][tid] + wacc[1][tid] + wacc[2][tid] + wacc[3][tid];
        part5[((size_t)b * 16 + tid) * NBLK + blockIdx.x] = v;
    }
}

// ---------------------------------------------------------------------------
// K6: reduce part5 (wave b = batch b) + final combine -> scalar loss.
// ---------------------------------------------------------------------------
__global__ __launch_bounds__(512)
void k6_final(const float* __restrict__ k1s, const float* __restrict__ kms,
              const float* __restrict__ part5, float* __restrict__ out) {
    const int tid = threadIdx.x;
    const int b = tid >> 6, lane = tid & 63;
    __shared__ float KmS[BATCH * 32];
    __shared__ float slS[BATCH][16];
    __shared__ float laS[BATCH], ldS[BATCH];
    if (tid < BATCH * 32) KmS[tid] = kms[tid];

    // reduce part5: wave b handles its batch's 16 slots
    for (int j = 0; j < 16; ++j) {
        const float* p = part5 + ((size_t)b * 16 + j) * NBLK;
        float v = 0.f;
        for (int i = lane; i < NBLK; i += 64) v += p[i];
        v = wred64(v);
        if (lane == 0) slS[b][j] = v;
    }
    __syncthreads();

    const float* s1 = k1s + b * NP;
    float aggs = 0.f, aggc = 0.f;
    if (lane >= 1 && lane <= 8) {
        float ctv = slS[b][8 + lane - 1];
        float ckv = s1[J_CNTK + lane - 1];
        if (ctv > 0.f && ckv > 0.f) {
            aggs = slS[b][lane - 1] / fmaxf(ctv, 1.f);
            aggc = 1.f;
        }
    }
    float diss = 0.f, disc = 0.f;
    {
        int i = 1 + (lane >> 3), j = 1 + (lane & 7);
        if (i != j && s1[J_CNTK + i - 1] > 0.f && s1[J_CNTK + j - 1] > 0.f) {
            float d2 = 0.f;
#pragma unroll
            for (int c = 0; c < 4; ++c) {
                float df = KmS[b * 32 + (i - 1) * 4 + c] -
                           KmS[b * 32 + (j - 1) * 4 + c];
                d2 = fmaf(df, df, d2);
            }
            float kd = sqrtf(d2);
            float t = fmaxf(3.f - kd, 0.f);
            diss = logf(t * t + 1.f);
            disc = 1.f;
        }
    }
    aggs = wred64(aggs); aggc = wred64(aggc);
    diss = wred64(diss); disc = wred64(disc);
    if (lane == 0) {
        laS[b] = aggs / fmaxf(aggc, 1.f);
        ldS[b] = diss / fmaxf(disc, 1.f);
    }
    __syncthreads();
    if (tid == 0) {
        float Lt = 0.f, Lk = 0.f, La = 0.f, Ld = 0.f;
        for (int bb = 0; bb < BATCH; ++bb) {
            const float* a = k1s + bb * NP;
            Lk += 1.f - 2.f * a[J_AK] / ((a[J_BK] + 1e-6f) + (a[J_CK] + 1e-6f));
            float btv = a[J_BTP] + a[J_BTN];
            Lt += 1.f - 2.f * a[J_AT] / ((btv + 1e-6f) + (a[J_CPOS] + 1e-6f));
            La += laS[bb]; Ld += ldS[bb];
        }
        out[0] = Lt / BATCH + 0.5f * (Lk / BATCH) + 0.25f * (La / BATCH + Ld / BATCH);
    }
}

// ---------------------------------------------------------------------------
extern "C" void kernel_launch(void* const* d_in, const int* in_sizes, int n_in,
                              void* d_out, int out_size, void* d_ws, size_t ws_size,
                              hipStream_t stream) {
    (void)in_sizes; (void)n_in; (void)out_size; (void)ws_size;
    const f4v* Tl = (const f4v*)d_in[0];   // pre_text_logits
    const f4v* Kl = (const f4v*)d_in[1];   // pre_kernel_logits
    const f4v* Fv = (const f4v*)d_in[2];   // similarity_vector [B,C,H,W]
    const f4v* Tm = (const f4v*)d_in[5];   // train_mask
    const i4v* Ltk = (const i4v*)d_in[6];  // gt_text_key
    const i4v* Lkk = (const i4v*)d_in[7];  // gt_kernel_key
    float* out = (float*)d_out;

    // ws layout (4B units). memset: only minkeyinv (32 B).
    unsigned* minkeyinv = (unsigned*)d_ws;               // 8
    float* thr = (float*)(minkeyinv + BATCH);            // 8
    unsigned* fb = (unsigned*)(thr + BATCH);             // 8
    float* k1s = (float*)(fb + BATCH);                   // 8*48 = 384
    float* kms = k1s + BATCH * NP;                       // 8*32 = 256
    float* part = kms + BATCH * 32;                      // 8*48*200 = 76800
    float* part5 = part + (size_t)BATCH * NP * NBLK;     // 8*16*200 = 25600
    unsigned* pk8 = (unsigned*)(part5 + (size_t)BATCH * 16 * NBLK); // 8*HW4

    hipMemsetAsync(minkeyinv, 0, BATCH * 4, stream);

    dim3 g(NBLK, BATCH);          // (200, 8): 512 float4 per block
    k1_main<<<g, 256, 0, stream>>>(Tl, Kl, Fv, Tm, Ltk, Lkk, part, pk8, minkeyinv);
    k1_reduce<<<BATCH, 256, 0, stream>>>(part, minkeyinv, (const float*)d_in[0],
                                         (const unsigned char*)pk8,
                                         k1s, kms, thr, fb);
    k_negfix<<<dim3(100, BATCH), 256, 0, stream>>>(Tl, pk8, fb, thr, k1s);
    k5_agg<<<g, 256, 0, stream>>>(pk8, Fv, kms, part5);
    k6_final<<<1, 512, 0, stream>>>(k1s, kms, part5, out);
}

// Round 16
// 78.618 us; speedup vs baseline: 3.4327x; 1.2184x over previous
//
#include <hip/hip_runtime.h>
#include <math.h>

#define BATCH 8
#define HW_N 409600          // 640*640
#define HW4 (HW_N / 4)       // 102400
#define NBLK 200             // pixel-kernel blocks per batch (512 float4/block)

// k1s per-batch reduction slots
#define NP 48
#define J_AK   0             // kernel dice: sum pk*gk*km
#define J_BK   1             //              sum pk*pk*km
#define J_CK   2             //              sum gk*km
#define J_AT   3             // text dice:   sum pt over pos&tm
#define J_BTP  4             //              sum pt^2 over pos&tm
#define J_BTN  5             //              sum pt^2 over ALL neg&tm (negfix subtracts)
#define J_CPOS 6             // count(pos & tm)
#define J_CNEG 7             // count(!pos)
#define J_CNTK 8             // +(s-1), s=1..8
#define J_SUMK 16            // +(s-1)*4+c  (32)

typedef float f4v __attribute__((ext_vector_type(4)));
typedef int   i4v __attribute__((ext_vector_type(4)));

__device__ __forceinline__ unsigned f2key(float x) {
    unsigned u = __float_as_uint(x);
    return (u & 0x80000000u) ? ~u : (u | 0x80000000u);
}
__device__ __forceinline__ float key2f(unsigned k) {
    unsigned u = (k & 0x80000000u) ? (k & 0x7fffffffu) : ~k;
    return __uint_as_float(u);
}
__device__ __forceinline__ float wred64(float v) {
#pragma unroll
    for (int o = 32; o > 0; o >>= 1) v += __shfl_xor(v, o, 64);
    return v;
}
__device__ __forceinline__ float wredmin64(float v) {
#pragma unroll
    for (int o = 32; o > 0; o >>= 1) v = fminf(v, __shfl_xor(v, o, 64));
    return v;
}

// ---------------------------------------------------------------------------
// K1: heavy pass (proven 42µs config: 2 float4/thread, 20-load pinned batch).
// Per-block partials -> part[] (contention-free); sum_k/cnt_k via LDS atomics.
// ---------------------------------------------------------------------------
__global__ __launch_bounds__(256)
void k1_main(const f4v* __restrict__ Tl, const f4v* __restrict__ Kl,
             const f4v* __restrict__ Fv, const f4v* __restrict__ Tm,
             const i4v* __restrict__ Ltk, const i4v* __restrict__ Lkk,
             float* __restrict__ part, unsigned* __restrict__ pk8,
             unsigned* __restrict__ minkeyinv) {
    const int b = blockIdx.y;
    const int tid = threadIdx.x;
    const int wid = tid >> 6, lane = tid & 63;
    const long base4 = (long)b * HW4;
    const long f04 = (long)b * 4 * HW4;

    __shared__ float sK[32];
    __shared__ unsigned cKs[8];
    __shared__ float wacc[4][8];
    __shared__ float wmin[4];
    if (tid < 32) sK[tid] = 0.f;
    else if (tid < 40) cKs[tid - 32] = 0u;
    __syncthreads();

    const int i0 = blockIdx.x * 512 + tid;
    const int i1 = i0 + 256;

    // ---- issue ALL 20 loads, then pin (batched issue, one wait) ----
    const f4v tlA = Tl[base4 + i0],  tlB = Tl[base4 + i1];
    const f4v klA = Kl[base4 + i0],  klB = Kl[base4 + i1];
    const f4v tmA = Tm[base4 + i0],  tmB = Tm[base4 + i1];
    const i4v ltA = Ltk[base4 + i0], ltB = Ltk[base4 + i1];
    const i4v lkA = Lkk[base4 + i0], lkB = Lkk[base4 + i1];
    const f4v f0A = Fv[f04 + i0],            f0B = Fv[f04 + i1];
    const f4v f1A = Fv[f04 + HW4 + i0],      f1B = Fv[f04 + HW4 + i1];
    const f4v f2A = Fv[f04 + 2 * HW4 + i0],  f2B = Fv[f04 + 2 * HW4 + i1];
    const f4v f3A = Fv[f04 + 3 * HW4 + i0],  f3B = Fv[f04 + 3 * HW4 + i1];
    asm volatile("" ::
        "v"(tlA.x), "v"(tlB.x), "v"(klA.x), "v"(klB.x), "v"(tmA.x), "v"(tmB.x),
        "v"(f0A.x), "v"(f0B.x), "v"(f1A.x), "v"(f1B.x),
        "v"(f2A.x), "v"(f2B.x), "v"(f3A.x), "v"(f3B.x),
        "v"(ltA.x), "v"(ltB.x), "v"(lkA.x), "v"(lkB.x));

    float r0 = 0.f, r1 = 0.f, r2 = 0.f, r3 = 0.f, r4 = 0.f, r5 = 0.f;
    float cpos = 0.f, cneg = 0.f;
    float vmin = INFINITY;

#pragma unroll
    for (int it = 0; it < 2; ++it) {
        const f4v tl4 = it ? tlB : tlA;
        const f4v kl4 = it ? klB : klA;
        const f4v tm4 = it ? tmB : tmA;
        const i4v lt4 = it ? ltB : ltA;
        const i4v lk4 = it ? lkB : lkA;
        const f4v F0v = it ? f0B : f0A;
        const f4v F1v = it ? f1B : f1A;
        const f4v F2v = it ? f2B : f2A;
        const f4v F3v = it ? f3B : f3A;
        unsigned pkw = 0u;
#pragma unroll
        for (int p = 0; p < 4; ++p) {
            float tl = tl4[p], kl = kl4[p], m = tm4[p];
            int ltk = lt4[p], lkk = lk4[p];
            bool tmb = m > 0.5f;
            bool selt = tl > 0.f;      // sigmoid(x)>0.5 <=> x>0
            bool selk = kl > 0.f;
            bool pos = ltk > 0;        // gt_text == (gt_text_key > 0)
            float gkf = (lkk > 0) ? 1.f : 0.f;
            float km = (selt && tmb) ? 1.f : 0.f;
            float pkv = 1.f / (1.f + __expf(-kl));
            float ptv = 1.f / (1.f + __expf(-tl));
            r0 = fmaf(pkv * gkf, km, r0);
            r1 = fmaf(pkv * pkv, km, r1);
            r2 = fmaf(gkf, km, r2);
            float ptm = (pos && tmb) ? 1.f : 0.f;
            float ntm = (!pos && tmb) ? 1.f : 0.f;
            r3 = fmaf(ptv, ptm, r3);
            r4 = fmaf(ptv * ptv, ptm, r4);
            r5 = fmaf(ptv * ptv, ntm, r5);
            cpos += ptm;
            cneg += pos ? 0.f : 1.f;
            vmin = fminf(vmin, pos ? INFINITY : tl);
            int lk = (selk && tmb) ? lkk : 0;
            if (lk > 0) {
                atomicAdd(&sK[(lk - 1) * 4 + 0], F0v[p]);
                atomicAdd(&sK[(lk - 1) * 4 + 1], F1v[p]);
                atomicAdd(&sK[(lk - 1) * 4 + 2], F2v[p]);
                atomicAdd(&sK[(lk - 1) * 4 + 3], F3v[p]);
                atomicAdd(&cKs[lk - 1], 1u);
            }
            pkw |= ((tmb ? 1u : 0u) | (selt ? 2u : 0u) | ((unsigned)ltk << 2)) << (8 * p);
        }
        pk8[base4 + (it ? i1 : i0)] = pkw;
    }

    r0 = wred64(r0); r1 = wred64(r1); r2 = wred64(r2);
    r3 = wred64(r3); r4 = wred64(r4); r5 = wred64(r5);
    cpos = wred64(cpos); cneg = wred64(cneg);
    vmin = wredmin64(vmin);
    if (lane == 0) {
        wacc[wid][0] = r0; wacc[wid][1] = r1; wacc[wid][2] = r2;
        wacc[wid][3] = r3; wacc[wid][4] = r4; wacc[wid][5] = r5;
        wacc[wid][6] = cpos; wacc[wid][7] = cneg;
        wmin[wid] = vmin;
    }
    __syncthreads();
    if (tid < NP) {
        float v;
        if (tid < 8)       v = wacc[0][tid] + wacc[1][tid] + wacc[2][tid] + wacc[3][tid];
        else if (tid < 16) v = (float)cKs[tid - 8];
        else               v = sK[tid - 16];
        part[((size_t)b * NP + tid) * NBLK + blockIdx.x] = v;
    }
    if (tid == 48) {
        float mn = fminf(fminf(wmin[0], wmin[1]), fminf(wmin[2], wmin[3]));
        if (mn < INFINITY) atomicMax(&minkeyinv[b], ~f2key(mn));
    }
}

// ---------------------------------------------------------------------------
// K1R: reduce per-block partials, OHEM decision, kernel means.
// ---------------------------------------------------------------------------
__global__ __launch_bounds__(256)
void k1_reduce(const float* __restrict__ part, const unsigned* __restrict__ minkeyinv,
               float* __restrict__ k1s, float* __restrict__ kms,
               float* __restrict__ thr, unsigned* __restrict__ kval,
               unsigned* __restrict__ fb) {
    const int b = blockIdx.x;
    const int tid = threadIdx.x, wid = tid >> 6, lane = tid & 63;
    __shared__ float ss[NP];
    for (int j = wid; j < NP; j += 4) {
        const float* p = part + ((size_t)b * NP + j) * NBLK;
        float v = 0.f;
        for (int i = lane; i < NBLK; i += 64) v += p[i];
        v = wred64(v);
        if (lane == 0) ss[j] = v;
    }
    __syncthreads();
    if (tid == 0) {
        unsigned pos = (unsigned)(ss[J_CPOS] + 0.5f);
        unsigned neg = (unsigned)(ss[J_CNEG] + 0.5f);
        unsigned k = min(3u * pos, neg);
        kval[b] = k;
        if (pos == 0u || k == 0u) { thr[b] = -INFINITY; fb[b] = 1u; }
        else if (k == neg)        { thr[b] = key2f(~minkeyinv[b]); fb[b] = 1u; }
        else                      { fb[b] = 0u; }   // rare: radix path
    }
    if (tid < NP) k1s[b * NP + tid] = ss[tid];
    if (tid >= 64 && tid < 96) {
        int t = tid - 64, s = t >> 2;
        kms[b * 32 + t] = ss[J_SUMK + t] / fmaxf(ss[J_CNTK + s], 1.f);
    }
}

// ---------------------------------------------------------------------------
// K_RARE: exact k-th-largest negative logit via 4-pass radix select.
// Early-exits in the common (fb=1) case.
// ---------------------------------------------------------------------------
__global__ __launch_bounds__(256)
void k_rare(const float* __restrict__ Tl, const unsigned char* __restrict__ pk8b,
            const unsigned* __restrict__ fb, const unsigned* __restrict__ kval,
            float* __restrict__ thr) {
    const int b = blockIdx.x;
    if (fb[b]) return;
    __shared__ unsigned hist[256];
    __shared__ unsigned sj, spre;
    const long base = (long)b * HW_N;
    if (threadIdx.x == 0) { sj = kval[b]; spre = 0u; }
    __syncthreads();
    for (int pass = 0; pass < 4; ++pass) {
        const int shift = 24 - 8 * pass;
        hist[threadIdx.x] = 0u;
        __syncthreads();
        const unsigned pref = spre;
        for (int i = threadIdx.x; i < HW_N; i += 256) {
            if ((pk8b[base + i] >> 2) != 0u) continue;   // pos pixel
            unsigned key = f2key(Tl[base + i]);
            if (pass == 0 || (key >> (shift + 8)) == pref)
                atomicAdd(&hist[(key >> shift) & 0xFFu], 1u);
        }
        __syncthreads();
        if (threadIdx.x == 0) {
            unsigned j = sj, cum = 0;
            for (int d = 255; d >= 0; --d) {
                cum += hist[d];
                if (cum >= j) {
                    sj = j - (cum - hist[d]);
                    spre = (pref << 8) | (unsigned)d;
                    break;
                }
            }
        }
        __syncthreads();
    }
    if (threadIdx.x == 0) thr[b] = key2f(spre);
}

// ---------------------------------------------------------------------------
// K_NEGFIX: rare path only — SUBTRACT pt^2 of excluded negatives (tl < thr).
// ---------------------------------------------------------------------------
__global__ __launch_bounds__(256)
void k_negfix(const f4v* __restrict__ Tl, const unsigned* __restrict__ pk8,
              const unsigned* __restrict__ fb, const float* __restrict__ thr,
              float* __restrict__ k1s) {
    const int b = blockIdx.y;
    if (fb[b]) return;
    const int tid = threadIdx.x;
    const long base4 = (long)b * HW4;
    const float tb = thr[b];
    float acc = 0.f;
#pragma unroll
    for (int j = 0; j < 4; ++j) {
        const int i4 = blockIdx.x * 1024 + j * 256 + tid;
        const f4v tl4 = Tl[base4 + i4];
        const unsigned pkw = pk8[base4 + i4];
#pragma unroll
        for (int p = 0; p < 4; ++p) {
            unsigned byte = (pkw >> (8 * p)) & 0xFFu;
            bool tmb = byte & 1u;
            bool neg = (byte >> 2) == 0u;
            float tl = tl4[p];
            if (neg && tmb && tl < tb) {
                float pt = 1.f / (1.f + __expf(-tl));
                acc = fmaf(pt, pt, acc);
            }
        }
    }
    acc = wred64(acc);
    __shared__ float wa[4];
    if ((tid & 63) == 0) wa[tid >> 6] = acc;
    __syncthreads();
    if (tid == 0) {
        float s = wa[0] + wa[1] + wa[2] + wa[3];
        if (s != 0.f) atomicAdd(&k1s[b * NP + J_BTN], -s);
    }
}

// ---------------------------------------------------------------------------
// K5: aggregation pass — Fv + packed plane, 2 float4/thread, pinned batch;
// register accumulators for sum_l and cnt_t; 16 global atomics per block
// (low contention — hidden under execution).
// ---------------------------------------------------------------------------
__global__ __launch_bounds__(256)
void k5_agg(const unsigned* __restrict__ pk8, const f4v* __restrict__ Fv,
            const float* __restrict__ kms, float* __restrict__ slg) {
    const int b = blockIdx.y;
    const int tid = threadIdx.x, wid = tid >> 6, lane = tid & 63;
    __shared__ float Kml[32];
    __shared__ float wacc[4][16];
    if (tid < 32) Kml[tid] = kms[b * 32 + tid];
    __syncthreads();
    const long base4 = (long)b * HW4;
    const long f04 = (long)b * 4 * HW4;
    const int i0 = blockIdx.x * 512 + tid;
    const int i1 = i0 + 256;

    // ---- issue ALL 10 loads, then pin ----
    const unsigned pkwA = pk8[base4 + i0], pkwB = pk8[base4 + i1];
    const f4v f0A = Fv[f04 + i0],           f0B = Fv[f04 + i1];
    const f4v f1A = Fv[f04 + HW4 + i0],     f1B = Fv[f04 + HW4 + i1];
    const f4v f2A = Fv[f04 + 2 * HW4 + i0], f2B = Fv[f04 + 2 * HW4 + i1];
    const f4v f3A = Fv[f04 + 3 * HW4 + i0], f3B = Fv[f04 + 3 * HW4 + i1];
    asm volatile("" ::
        "v"(pkwA), "v"(pkwB),
        "v"(f0A.x), "v"(f0B.x), "v"(f1A.x), "v"(f1B.x),
        "v"(f2A.x), "v"(f2B.x), "v"(f3A.x), "v"(f3B.x));

    float sl8[8] = {0.f, 0.f, 0.f, 0.f, 0.f, 0.f, 0.f, 0.f};
    float ct8[8] = {0.f, 0.f, 0.f, 0.f, 0.f, 0.f, 0.f, 0.f};

#pragma unroll
    for (int it = 0; it < 2; ++it) {
        const unsigned pkw = it ? pkwB : pkwA;
        const f4v F0v = it ? f0B : f0A;
        const f4v F1v = it ? f1B : f1A;
        const f4v F2v = it ? f2B : f2A;
        const f4v F3v = it ? f3B : f3A;
#pragma unroll
        for (int p = 0; p < 4; ++p) {
            unsigned byte = (pkw >> (8 * p)) & 0xFFu;
            int lt = ((byte & 3u) == 3u) ? (int)(byte >> 2) : 0;
            int kb = (lt > 0 ? lt - 1 : 0) * 4;
            float d0 = F0v[p] - Kml[kb + 0];
            float d1 = F1v[p] - Kml[kb + 1];
            float d2 = F2v[p] - Kml[kb + 2];
            float d3 = F3v[p] - Kml[kb + 3];
            float d = sqrtf(fmaf(d0, d0, fmaf(d1, d1, fmaf(d2, d2, d3 * d3))));
            float t = fmaxf(d - 0.5f, 0.f);
            float pl = __logf(fmaf(t, t, 1.f));
#pragma unroll
            for (int s = 1; s <= 8; ++s) {
                float e = (lt == s) ? 1.f : 0.f;
                sl8[s - 1] = fmaf(e, pl, sl8[s - 1]);
                ct8[s - 1] += e;
            }
        }
    }

#pragma unroll
    for (int j = 0; j < 8; ++j) { sl8[j] = wred64(sl8[j]); ct8[j] = wred64(ct8[j]); }
    if (lane == 0) {
#pragma unroll
        for (int j = 0; j < 8; ++j) { wacc[wid][j] = sl8[j]; wacc[wid][8 + j] = ct8[j]; }
    }
    __syncthreads();
    if (tid < 16) {
        float v = wacc[0][tid] + wacc[1][tid] + wacc[2][tid] + wacc[3][tid];
        atomicAdd(&slg[b * 16 + tid], v);
    }
}

// ---------------------------------------------------------------------------
// K6: final combine -> scalar loss.
// ---------------------------------------------------------------------------
__global__ __launch_bounds__(512)
void k6_final(const float* __restrict__ k1s, const float* __restrict__ kms,
              const float* __restrict__ slg, float* __restrict__ out) {
    const int tid = threadIdx.x;
    const int b = tid >> 6, lane = tid & 63;
    __shared__ float KmS[BATCH * 32];
    __shared__ float laS[BATCH], ldS[BATCH];
    if (tid < BATCH * 32) KmS[tid] = kms[tid];
    __syncthreads();
    const float* s1 = k1s + b * NP;

    float aggs = 0.f, aggc = 0.f;
    if (lane >= 1 && lane <= 8) {
        float ctv = slg[b * 16 + 8 + lane - 1];
        float ckv = s1[J_CNTK + lane - 1];
        if (ctv > 0.f && ckv > 0.f) {
            aggs = slg[b * 16 + lane - 1] / fmaxf(ctv, 1.f);
            aggc = 1.f;
        }
    }
    float diss = 0.f, disc = 0.f;
    {
        int i = 1 + (lane >> 3), j = 1 + (lane & 7);
        if (i != j && s1[J_CNTK + i - 1] > 0.f && s1[J_CNTK + j - 1] > 0.f) {
            float d2 = 0.f;
#pragma unroll
            for (int c = 0; c < 4; ++c) {
                float df = KmS[b * 32 + (i - 1) * 4 + c] -
                           KmS[b * 32 + (j - 1) * 4 + c];
                d2 = fmaf(df, df, d2);
            }
            float kd = sqrtf(d2);
            float t = fmaxf(3.f - kd, 0.f);
            diss = logf(t * t + 1.f);
            disc = 1.f;
        }
    }
    aggs = wred64(aggs); aggc = wred64(aggc);
    diss = wred64(diss); disc = wred64(disc);
    if (lane == 0) {
        laS[b] = aggs / fmaxf(aggc, 1.f);
        ldS[b] = diss / fmaxf(disc, 1.f);
    }
    __syncthreads();
    if (tid == 0) {
        float Lt = 0.f, Lk = 0.f, La = 0.f, Ld = 0.f;
        for (int bb = 0; bb < BATCH; ++bb) {
            const float* a = k1s + bb * NP;
            Lk += 1.f - 2.f * a[J_AK] / ((a[J_BK] + 1e-6f) + (a[J_CK] + 1e-6f));
            float btv = a[J_BTP] + a[J_BTN];
            Lt += 1.f - 2.f * a[J_AT] / ((btv + 1e-6f) + (a[J_CPOS] + 1e-6f));
            La += laS[bb]; Ld += ldS[bb];
        }
        out[0] = Lt / BATCH + 0.5f * (Lk / BATCH) + 0.25f * (La / BATCH + Ld / BATCH);
    }
}

// ---------------------------------------------------------------------------
extern "C" void kernel_launch(void* const* d_in, const int* in_sizes, int n_in,
                              void* d_out, int out_size, void* d_ws, size_t ws_size,
                              hipStream_t stream) {
    (void)in_sizes; (void)n_in; (void)out_size; (void)ws_size;
    const f4v* Tl = (const f4v*)d_in[0];   // pre_text_logits
    const f4v* Kl = (const f4v*)d_in[1];   // pre_kernel_logits
    const f4v* Fv = (const f4v*)d_in[2];   // similarity_vector [B,C,H,W]
    const f4v* Tm = (const f4v*)d_in[5];   // train_mask
    const i4v* Ltk = (const i4v*)d_in[6];  // gt_text_key
    const i4v* Lkk = (const i4v*)d_in[7];  // gt_kernel_key
    float* out = (float*)d_out;

    // ws layout (4B units). memset region first: k1s, slg, minkeyinv.
    float* k1s = (float*)d_ws;                           // 8*48 = 384
    float* slg = k1s + BATCH * NP;                       // 8*16 = 128
    unsigned* minkeyinv = (unsigned*)(slg + BATCH * 16); // 8
    float* thr = (float*)(minkeyinv + BATCH);            // 8
    unsigned* kval = (unsigned*)(thr + BATCH);           // 8
    unsigned* fb = kval + BATCH;                         // 8
    float* kms = (float*)(fb + BATCH);                   // 8*32 = 256
    float* part = kms + BATCH * 32;                      // 8*48*200 = 76800
    unsigned* pk8 = (unsigned*)(part + (size_t)BATCH * NP * NBLK); // 8*HW4

    hipMemsetAsync(d_ws, 0, (size_t)(BATCH * NP + BATCH * 16 + BATCH) * 4, stream);

    dim3 g(NBLK, BATCH);
    k1_main<<<g, 256, 0, stream>>>(Tl, Kl, Fv, Tm, Ltk, Lkk, part, pk8, minkeyinv);
    k1_reduce<<<BATCH, 256, 0, stream>>>(part, minkeyinv, k1s, kms, thr, kval, fb);
    k_rare<<<BATCH, 256, 0, stream>>>((const float*)d_in[0],
                                      (const unsigned char*)pk8, fb, kval, thr);
    k_negfix<<<dim3(100, BATCH), 256, 0, stream>>>(Tl, pk8, fb, thr, k1s);
    k5_agg<<<g, 256, 0, stream>>>(pk8, Fv, kms, slg);
    k6_final<<<1, 512, 0, stream>>>(k1s, kms, slg, out);
}